// Round 1
// baseline (2352.893 us; speedup 1.0000x reference)
//
#include <hip/hip_runtime.h>
#include <math.h>

#define D_MODEL 1024
#define N_HEADS 16
#define DK      64
#define D_FF    4096
#define BB      2
#define SS      2048
#define ROWS    (BB * SS)          // 4096 token rows
#define EPS     1e-8f
#define NEGINF  -1e9f

union F4 { float4 v; float f[4]; };

// ---------------------------------------------------------------------------
// LayerNorm: one block per row. Matches torch: mean, unbiased std (ddof=1),
// eps added to std (not var). gamma/beta are scalars (shape (1,1,1)).
// ---------------------------------------------------------------------------
__global__ __launch_bounds__(256) void ln_kernel(const float* __restrict__ x,
                                                 const float* __restrict__ g,
                                                 const float* __restrict__ be,
                                                 float* __restrict__ out) {
    __shared__ float sm[8];
    const int row = blockIdx.x;
    const float4* xr = (const float4*)(x + (size_t)row * D_MODEL);
    float4 v = xr[threadIdx.x];                    // 4 elements / thread

    float s = v.x + v.y + v.z + v.w;
#pragma unroll
    for (int o = 32; o; o >>= 1) s += __shfl_xor(s, o);
    const int wid = threadIdx.x >> 6, lane = threadIdx.x & 63;
    if (lane == 0) sm[wid] = s;
    __syncthreads();
    const float mean = (sm[0] + sm[1] + sm[2] + sm[3]) * (1.0f / D_MODEL);

    const float dx = v.x - mean, dy = v.y - mean, dz = v.z - mean, dw = v.w - mean;
    float sq = dx * dx + dy * dy + dz * dz + dw * dw;
#pragma unroll
    for (int o = 32; o; o >>= 1) sq += __shfl_xor(sq, o);
    if (lane == 0) sm[4 + wid] = sq;
    __syncthreads();
    const float var = (sm[4] + sm[5] + sm[6] + sm[7]) * (1.0f / (D_MODEL - 1));
    const float inv = 1.0f / (sqrtf(var) + EPS);
    const float g0 = g[0], b0 = be[0];

    float4 o4;
    o4.x = g0 * dx * inv + b0;
    o4.y = g0 * dy * inv + b0;
    o4.z = g0 * dz * inv + b0;
    o4.w = g0 * dw * inv + b0;
    ((float4*)(out + (size_t)row * D_MODEL))[threadIdx.x] = o4;
}

// ---------------------------------------------------------------------------
// fp32 GEMM: C[M,N] = A[M,K] @ B[N,K]^T + bias[N]  (+ optional ReLU / residual)
// A row-major [M,K], B row-major [N,K] (== W in the reference, used as W^T).
// 64x64 tile, BK=32, 256 threads, 4x4 micro-tile per thread.
// ---------------------------------------------------------------------------
template <bool RELU, bool RES>
__global__ __launch_bounds__(256) void gemm_bt(const float* __restrict__ A,
                                               const float* __restrict__ B,
                                               const float* __restrict__ bias,
                                               const float* __restrict__ res,
                                               float* __restrict__ C,
                                               int M, int N, int K) {
    __shared__ float As[32][68];   // [k][m] transposed; row stride 68*4B = 16B-aligned
    __shared__ float Bs[32][68];   // [k][n]
    const int bm = blockIdx.y * 64;
    const int bn = blockIdx.x * 64;
    const int tid = threadIdx.x;
    const int ty = tid >> 4, tx = tid & 15;

    float acc[4][4] = {};

    for (int k0 = 0; k0 < K; k0 += 32) {
#pragma unroll
        for (int i = 0; i < 2; ++i) {
            const int idx = tid + i * 256;       // 0..511
            const int m  = idx >> 3;             // 0..63 tile row
            const int kv = idx & 7;              // float4 within the 32-wide k slab
            F4 a; a.v = *(const float4*)(A + (size_t)(bm + m) * K + k0 + kv * 4);
            As[kv * 4 + 0][m] = a.f[0];
            As[kv * 4 + 1][m] = a.f[1];
            As[kv * 4 + 2][m] = a.f[2];
            As[kv * 4 + 3][m] = a.f[3];
            F4 b; b.v = *(const float4*)(B + (size_t)(bn + m) * K + k0 + kv * 4);
            Bs[kv * 4 + 0][m] = b.f[0];
            Bs[kv * 4 + 1][m] = b.f[1];
            Bs[kv * 4 + 2][m] = b.f[2];
            Bs[kv * 4 + 3][m] = b.f[3];
        }
        __syncthreads();
#pragma unroll
        for (int k = 0; k < 32; ++k) {
            F4 a, b;
            a.v = *(const float4*)&As[k][ty * 4];
            b.v = *(const float4*)&Bs[k][tx * 4];
#pragma unroll
            for (int i = 0; i < 4; ++i)
#pragma unroll
                for (int j = 0; j < 4; ++j)
                    acc[i][j] = fmaf(a.f[i], b.f[j], acc[i][j]);
        }
        __syncthreads();
    }

#pragma unroll
    for (int i = 0; i < 4; ++i) {
        const int row = bm + ty * 4 + i;
        float* crow = C + (size_t)row * N + bn + tx * 4;
        const float* rrow = RES ? (res + (size_t)row * N + bn + tx * 4) : nullptr;
        F4 o;
#pragma unroll
        for (int j = 0; j < 4; ++j) {
            float val = acc[i][j] + bias[bn + tx * 4 + j];
            if (RELU) val = fmaxf(val, 0.0f);
            if (RES) val += rrow[j];
            o.f[j] = val;
        }
        *(float4*)crow = o.v;
    }
}

// ---------------------------------------------------------------------------
// Fused flash-style attention (fp32). Grid: (S/64, B*H). Block: 256 threads.
// Q,K,V are [B*S, D_MODEL] with head h occupying columns h*64..h*64+63.
// Each block: one (b,h) and a 64-query tile; iterates 32 K/V tiles of 64 keys
// with online softmax. Writes ctx in [B,S,D_MODEL] layout (head-transpose fused).
// ---------------------------------------------------------------------------
__global__ __launch_bounds__(256) void attn_kernel(const float* __restrict__ Q,
                                                   const float* __restrict__ K,
                                                   const float* __restrict__ V,
                                                   const int* __restrict__ mask,
                                                   float* __restrict__ O) {
    __shared__ float Qt[DK][68];   // [d][q]   (transposed, pre-scaled by 1/8)
    __shared__ float Kt[DK][68];   // [d][k]   (transposed)
    __shared__ float Vs[64][68];   // [k][d]
    __shared__ float Ps[64][68];   // [q][k]

    const int qt = blockIdx.x;          // query tile, 0..31
    const int bh = blockIdx.y;          // 0..31
    const int b = bh >> 4, h = bh & 15;
    const size_t base = (size_t)b * SS * D_MODEL + (size_t)h * DK;
    const int tid = threadIdx.x;
    const int ty = tid >> 4, tx = tid & 15;
    const int q0 = qt * 64;
    const int* mrow = mask + (size_t)b * SS;

    // stage Q transposed, pre-scaled by 1/sqrt(dk)=0.125
#pragma unroll
    for (int i = 0; i < 4; ++i) {
        const int idx = tid + i * 256;  // 0..1023
        const int r = idx >> 4;         // query row 0..63
        const int cv = idx & 15;        // float4 group along d
        F4 q4; q4.v = *(const float4*)(Q + base + (size_t)(q0 + r) * D_MODEL + cv * 4);
        Qt[cv * 4 + 0][r] = q4.f[0] * 0.125f;
        Qt[cv * 4 + 1][r] = q4.f[1] * 0.125f;
        Qt[cv * 4 + 2][r] = q4.f[2] * 0.125f;
        Qt[cv * 4 + 3][r] = q4.f[3] * 0.125f;
    }

    float m_run[4], l_run[4], oa[4][4];
#pragma unroll
    for (int i = 0; i < 4; ++i) {
        m_run[i] = -1e30f;
        l_run[i] = 0.0f;
#pragma unroll
        for (int j = 0; j < 4; ++j) oa[i][j] = 0.0f;
    }

    for (int kt = 0; kt < SS / 64; ++kt) {
        const int k0 = kt * 64;
        __syncthreads();   // prior-iter LDS reads done (covers Q staging on iter 0)
#pragma unroll
        for (int i = 0; i < 4; ++i) {
            const int idx = tid + i * 256;
            const int r = idx >> 4;
            const int cv = idx & 15;
            F4 k4; k4.v = *(const float4*)(K + base + (size_t)(k0 + r) * D_MODEL + cv * 4);
            Kt[cv * 4 + 0][r] = k4.f[0];
            Kt[cv * 4 + 1][r] = k4.f[1];
            Kt[cv * 4 + 2][r] = k4.f[2];
            Kt[cv * 4 + 3][r] = k4.f[3];
            float4 v4 = *(const float4*)(V + base + (size_t)(k0 + r) * D_MODEL + cv * 4);
            *(float4*)&Vs[r][cv * 4] = v4;
        }
        __syncthreads();

        // S tile: s[i][j] = sum_d Qt[d][ty*4+i] * Kt[d][tx*4+j]
        float s[4][4] = {};
#pragma unroll
        for (int d = 0; d < DK; ++d) {
            F4 qv, kv;
            qv.v = *(const float4*)&Qt[d][ty * 4];
            kv.v = *(const float4*)&Kt[d][tx * 4];
#pragma unroll
            for (int i = 0; i < 4; ++i)
#pragma unroll
                for (int j = 0; j < 4; ++j)
                    s[i][j] = fmaf(qv.f[i], kv.f[j], s[i][j]);
        }

        // mask (shape [B,1,1,S] broadcast over queries)
        int mk[4];
#pragma unroll
        for (int j = 0; j < 4; ++j) mk[j] = mrow[k0 + tx * 4 + j];
#pragma unroll
        for (int i = 0; i < 4; ++i)
#pragma unroll
            for (int j = 0; j < 4; ++j)
                if (mk[j] == 0) s[i][j] = NEGINF;

        // online softmax per query row (reduce across tx lanes: xor 1,2,4,8)
#pragma unroll
        for (int i = 0; i < 4; ++i) {
            float rm = fmaxf(fmaxf(s[i][0], s[i][1]), fmaxf(s[i][2], s[i][3]));
            rm = fmaxf(rm, __shfl_xor(rm, 1));
            rm = fmaxf(rm, __shfl_xor(rm, 2));
            rm = fmaxf(rm, __shfl_xor(rm, 4));
            rm = fmaxf(rm, __shfl_xor(rm, 8));
            const float mn = fmaxf(m_run[i], rm);
            const float sc = __expf(m_run[i] - mn);
            F4 p;
#pragma unroll
            for (int j = 0; j < 4; ++j) p.f[j] = __expf(s[i][j] - mn);
            float rs = p.f[0] + p.f[1] + p.f[2] + p.f[3];
            rs += __shfl_xor(rs, 1);
            rs += __shfl_xor(rs, 2);
            rs += __shfl_xor(rs, 4);
            rs += __shfl_xor(rs, 8);
            l_run[i] = l_run[i] * sc + rs;
            m_run[i] = mn;
#pragma unroll
            for (int j = 0; j < 4; ++j) oa[i][j] *= sc;
            *(float4*)&Ps[ty * 4 + i][tx * 4] = p.v;
        }
        __syncthreads();

        // oa[i][j] += sum_kk Ps[ty*4+i][kk] * Vs[kk][tx*4+j]
#pragma unroll
        for (int kk = 0; kk < 64; kk += 4) {
            F4 p0, p1, p2, p3, v0, v1, v2, v3;
            p0.v = *(const float4*)&Ps[ty * 4 + 0][kk];
            p1.v = *(const float4*)&Ps[ty * 4 + 1][kk];
            p2.v = *(const float4*)&Ps[ty * 4 + 2][kk];
            p3.v = *(const float4*)&Ps[ty * 4 + 3][kk];
            v0.v = *(const float4*)&Vs[kk + 0][tx * 4];
            v1.v = *(const float4*)&Vs[kk + 1][tx * 4];
            v2.v = *(const float4*)&Vs[kk + 2][tx * 4];
            v3.v = *(const float4*)&Vs[kk + 3][tx * 4];
            F4 pr[4] = {p0, p1, p2, p3};
#pragma unroll
            for (int i = 0; i < 4; ++i)
#pragma unroll
                for (int j = 0; j < 4; ++j) {
                    float t = fmaf(pr[i].f[0], v0.f[j], oa[i][j]);
                    t = fmaf(pr[i].f[1], v1.f[j], t);
                    t = fmaf(pr[i].f[2], v2.f[j], t);
                    oa[i][j] = fmaf(pr[i].f[3], v3.f[j], t);
                }
        }
    }

    // finalize: divide by l, write ctx at [b, q0+row, h*64 + d]
#pragma unroll
    for (int i = 0; i < 4; ++i) {
        const float invl = 1.0f / l_run[i];
        F4 o;
#pragma unroll
        for (int j = 0; j < 4; ++j) o.f[j] = oa[i][j] * invl;
        *(float4*)(O + base + (size_t)(q0 + ty * 4 + i) * D_MODEL + tx * 4) = o.v;
    }
}

// ---------------------------------------------------------------------------
// Launch: LN1 -> Q,K,V GEMMs -> attention -> O-proj(+res) -> LN2 ->
//         FFN1(ReLU) -> FFN2(+res) -> d_out
// ---------------------------------------------------------------------------
extern "C" void kernel_launch(void* const* d_in, const int* in_sizes, int n_in,
                              void* d_out, int out_size, void* d_ws, size_t ws_size,
                              hipStream_t stream) {
    const float* x   = (const float*)d_in[0];
    const int*   msk = (const int*)d_in[1];
    const float* Wq  = (const float*)d_in[2];
    const float* bq  = (const float*)d_in[3];
    const float* Wk  = (const float*)d_in[4];
    const float* bk  = (const float*)d_in[5];
    const float* Wv  = (const float*)d_in[6];
    const float* bv  = (const float*)d_in[7];
    const float* Wo  = (const float*)d_in[8];
    const float* bo  = (const float*)d_in[9];
    const float* W1  = (const float*)d_in[10];
    const float* b1  = (const float*)d_in[11];
    const float* W2  = (const float*)d_in[12];
    const float* b2  = (const float*)d_in[13];
    const float* g1  = (const float*)d_in[14];
    const float* be1 = (const float*)d_in[15];
    const float* g2  = (const float*)d_in[16];
    const float* be2 = (const float*)d_in[17];
    float* out = (float*)d_out;

    float* ws  = (float*)d_ws;
    float* h    = ws;                          // [4096,1024]
    float* qb   = h   + (size_t)ROWS * D_MODEL;
    float* kb   = qb  + (size_t)ROWS * D_MODEL;
    float* vb   = kb  + (size_t)ROWS * D_MODEL;
    float* ctx  = vb  + (size_t)ROWS * D_MODEL;
    float* xat  = ctx + (size_t)ROWS * D_MODEL;
    float* h2   = xat + (size_t)ROWS * D_MODEL;
    float* ff1  = h2  + (size_t)ROWS * D_MODEL; // [4096,4096]

    const dim3 blk(256);
    const dim3 gD(D_MODEL / 64, ROWS / 64);     // N=1024 GEMMs
    const dim3 gF(D_FF / 64, ROWS / 64);        // N=4096 GEMM

    ln_kernel<<<ROWS, blk, 0, stream>>>(x, g1, be1, h);
    gemm_bt<false, false><<<gD, blk, 0, stream>>>(h, Wq, bq, nullptr, qb, ROWS, D_MODEL, D_MODEL);
    gemm_bt<false, false><<<gD, blk, 0, stream>>>(h, Wk, bk, nullptr, kb, ROWS, D_MODEL, D_MODEL);
    gemm_bt<false, false><<<gD, blk, 0, stream>>>(h, Wv, bv, nullptr, vb, ROWS, D_MODEL, D_MODEL);
    attn_kernel<<<dim3(SS / 64, BB * N_HEADS), blk, 0, stream>>>(qb, kb, vb, msk, ctx);
    gemm_bt<false, true><<<gD, blk, 0, stream>>>(ctx, Wo, bo, x, xat, ROWS, D_MODEL, D_MODEL);
    ln_kernel<<<ROWS, blk, 0, stream>>>(xat, g2, be2, h2);
    gemm_bt<true, false><<<gF, blk, 0, stream>>>(h2, W1, b1, nullptr, ff1, ROWS, D_FF, D_MODEL);
    gemm_bt<false, true><<<gD, blk, 0, stream>>>(ff1, W2, b2, xat, out, ROWS, D_MODEL, D_FF);
}

// Round 2
// 1179.294 us; speedup vs baseline: 1.9952x; 1.9952x over previous
//
#include <hip/hip_runtime.h>
#include <math.h>

#define D_MODEL 1024
#define N_HEADS 16
#define DK      64
#define D_FF    4096
#define BB      2
#define SS      2048
#define ROWS    (BB * SS)          // 4096 token rows
#define EPS     1e-8f
#define NEGINF  -1e9f

union F4 { float4 v; float f[4]; };

typedef __attribute__((ext_vector_type(8))) short   bf16x8;  // 8 bf16 in 4 VGPRs
typedef __attribute__((ext_vector_type(4))) float   f32x4;

// round-to-nearest-even fp32 -> bf16
__device__ __forceinline__ unsigned short f2bf(float f) {
    union { float f; unsigned u; } a; a.f = f;
    unsigned r = a.u + 0x7FFFu + ((a.u >> 16) & 1u);
    return (unsigned short)(r >> 16);
}

// async global->LDS, 16 bytes per lane. LDS dest: wave-uniform base + lane*16.
__device__ __forceinline__ void gload16(const void* g, void* l) {
    __builtin_amdgcn_global_load_lds(
        (const __attribute__((address_space(1))) unsigned int*)g,
        (__attribute__((address_space(3))) unsigned int*)l, 16, 0, 0);
}

// ---------------------------------------------------------------------------
// LayerNorm -> bf16 output. One block (256 thr) per row; matches torch
// semantics: mean, unbiased std (ddof=1), eps added to std.
// ---------------------------------------------------------------------------
__global__ __launch_bounds__(256) void ln_bf16_kernel(const float* __restrict__ x,
                                                      const float* __restrict__ g,
                                                      const float* __restrict__ be,
                                                      unsigned short* __restrict__ out) {
    __shared__ float sm[8];
    const int row = blockIdx.x;
    const float4* xr = (const float4*)(x + (size_t)row * D_MODEL);
    float4 v = xr[threadIdx.x];

    float s = v.x + v.y + v.z + v.w;
#pragma unroll
    for (int o = 32; o; o >>= 1) s += __shfl_xor(s, o);
    const int wid = threadIdx.x >> 6, lane = threadIdx.x & 63;
    if (lane == 0) sm[wid] = s;
    __syncthreads();
    const float mean = (sm[0] + sm[1] + sm[2] + sm[3]) * (1.0f / D_MODEL);

    const float dx = v.x - mean, dy = v.y - mean, dz = v.z - mean, dw = v.w - mean;
    float sq = dx * dx + dy * dy + dz * dz + dw * dw;
#pragma unroll
    for (int o = 32; o; o >>= 1) sq += __shfl_xor(sq, o);
    if (lane == 0) sm[4 + wid] = sq;
    __syncthreads();
    const float var = (sm[4] + sm[5] + sm[6] + sm[7]) * (1.0f / (D_MODEL - 1));
    const float inv = 1.0f / (sqrtf(var) + EPS);
    const float g0 = g[0], b0 = be[0];

    ushort4 o4;
    o4.x = f2bf(g0 * dx * inv + b0);
    o4.y = f2bf(g0 * dy * inv + b0);
    o4.z = f2bf(g0 * dz * inv + b0);
    o4.w = f2bf(g0 * dw * inv + b0);
    ((ushort4*)(out + (size_t)row * D_MODEL))[threadIdx.x] = o4;
}

// ---------------------------------------------------------------------------
// fp32 -> bf16 cast (weights). 4 elems/thread.
// ---------------------------------------------------------------------------
__global__ __launch_bounds__(256) void cast_bf16_kernel(const float* __restrict__ in,
                                                        unsigned short* __restrict__ out,
                                                        int n4) {
    const int i = blockIdx.x * 256 + threadIdx.x;
    if (i < n4) {
        float4 v = ((const float4*)in)[i];
        ushort4 o = { f2bf(v.x), f2bf(v.y), f2bf(v.z), f2bf(v.w) };
        ((ushort4*)out)[i] = o;
    }
}

// ---------------------------------------------------------------------------
// bf16 MFMA GEMM (m97 structure): C[M,N] = A[M,K] @ B[N,K]^T + bias
// A,B bf16 row-major (K contiguous). 128x128 tile, BK=32, 256 thr = 4 waves
// in 2x2; each wave computes 64x64 = 4x4 fragments of 16x16x32.
// Staging via global_load_lds width=16 into linear LDS [128][32] bf16.
// Epilogue fuses bias (+ReLU) (+fp32 residual); output fp32 or bf16.
// ---------------------------------------------------------------------------
template <bool RELU, bool RES, bool OUTBF>
__global__ __launch_bounds__(256) void gemm_bf16(const unsigned short* __restrict__ A,
                                                 const unsigned short* __restrict__ B,
                                                 const float* __restrict__ bias,
                                                 const float* __restrict__ res,
                                                 void* __restrict__ Cout,
                                                 int M, int N, int K) {
    __shared__ unsigned short As[128 * 32];   // [row][k] linear, row = 64 B
    __shared__ unsigned short Bs[128 * 32];

    const int bm = blockIdx.y * 128;
    const int bn = blockIdx.x * 128;
    const int tid  = threadIdx.x;
    const int lane = tid & 63;
    const int wv   = tid >> 6;          // 0..3
    const int wr   = wv >> 1;           // wave row (0..1)
    const int wc   = wv & 1;            // wave col (0..1)
    const int lr   = lane & 15;         // fragment row/col index
    const int lq   = lane >> 4;         // k-block / row-quad

    f32x4 acc[4][4];
#pragma unroll
    for (int m = 0; m < 4; ++m)
#pragma unroll
        for (int n = 0; n < 4; ++n)
            acc[m][n] = (f32x4){0.f, 0.f, 0.f, 0.f};

    // per-lane staging source offsets: wave wv covers tile rows [wv*32, wv*32+32)
    const int srow = wv * 32 + (lane >> 2);       // +0 / +16 per issue
    const int scol = (lane & 3) * 8;              // bf16 elements within BK=32

    for (int k0 = 0; k0 < K; k0 += 32) {
        __syncthreads();   // previous iteration's LDS reads complete
        // A tile: 128 rows x 32 bf16
        gload16(A + (size_t)(bm + srow) * K + k0 + scol,        &As[(wv * 32) * 32]);
        gload16(A + (size_t)(bm + srow + 16) * K + k0 + scol,   &As[(wv * 32 + 16) * 32]);
        gload16(B + (size_t)(bn + srow) * K + k0 + scol,        &Bs[(wv * 32) * 32]);
        gload16(B + (size_t)(bn + srow + 16) * K + k0 + scol,   &Bs[(wv * 32 + 16) * 32]);
        __syncthreads();   // vmcnt(0) drained by compiler before barrier

        bf16x8 af[4], bf[4];
#pragma unroll
        for (int m = 0; m < 4; ++m)
            af[m] = *(const bf16x8*)&As[(wr * 64 + m * 16 + lr) * 32 + lq * 8];
#pragma unroll
        for (int n = 0; n < 4; ++n)
            bf[n] = *(const bf16x8*)&Bs[(wc * 64 + n * 16 + lr) * 32 + lq * 8];

#pragma unroll
        for (int m = 0; m < 4; ++m)
#pragma unroll
            for (int n = 0; n < 4; ++n)
                acc[m][n] = __builtin_amdgcn_mfma_f32_16x16x32_bf16(af[m], bf[n], acc[m][n], 0, 0, 0);
    }

    // epilogue: C/D layout col = lane&15, row = (lane>>4)*4 + reg
#pragma unroll
    for (int n = 0; n < 4; ++n) {
        const int col = bn + wc * 64 + n * 16 + lr;
        const float bv = bias[col];
#pragma unroll
        for (int m = 0; m < 4; ++m) {
#pragma unroll
            for (int r = 0; r < 4; ++r) {
                const int row = bm + wr * 64 + m * 16 + lq * 4 + r;
                float v = acc[m][n][r] + bv;
                if (RELU) v = fmaxf(v, 0.0f);
                if (RES)  v += res[(size_t)row * N + col];
                if (OUTBF) ((unsigned short*)Cout)[(size_t)row * N + col] = f2bf(v);
                else       ((float*)Cout)[(size_t)row * N + col] = v;
            }
        }
    }
}

// ---------------------------------------------------------------------------
// Fused flash-style attention (fp32 compute, bf16 ctx output).
// Grid: (S/64, B*H). Block: 256 threads.
// ---------------------------------------------------------------------------
__global__ __launch_bounds__(256) void attn_kernel(const float* __restrict__ Q,
                                                   const float* __restrict__ K,
                                                   const float* __restrict__ V,
                                                   const int* __restrict__ mask,
                                                   unsigned short* __restrict__ O) {
    __shared__ float Qt[DK][68];
    __shared__ float Kt[DK][68];
    __shared__ float Vs[64][68];
    __shared__ float Ps[64][68];

    const int qt = blockIdx.x;
    const int bh = blockIdx.y;
    const int b = bh >> 4, h = bh & 15;
    const size_t base = (size_t)b * SS * D_MODEL + (size_t)h * DK;
    const int tid = threadIdx.x;
    const int ty = tid >> 4, tx = tid & 15;
    const int q0 = qt * 64;
    const int* mrow = mask + (size_t)b * SS;

#pragma unroll
    for (int i = 0; i < 4; ++i) {
        const int idx = tid + i * 256;
        const int r = idx >> 4;
        const int cv = idx & 15;
        F4 q4; q4.v = *(const float4*)(Q + base + (size_t)(q0 + r) * D_MODEL + cv * 4);
        Qt[cv * 4 + 0][r] = q4.f[0] * 0.125f;
        Qt[cv * 4 + 1][r] = q4.f[1] * 0.125f;
        Qt[cv * 4 + 2][r] = q4.f[2] * 0.125f;
        Qt[cv * 4 + 3][r] = q4.f[3] * 0.125f;
    }

    float m_run[4], l_run[4], oa[4][4];
#pragma unroll
    for (int i = 0; i < 4; ++i) {
        m_run[i] = -1e30f;
        l_run[i] = 0.0f;
#pragma unroll
        for (int j = 0; j < 4; ++j) oa[i][j] = 0.0f;
    }

    for (int kt = 0; kt < SS / 64; ++kt) {
        const int k0 = kt * 64;
        __syncthreads();
#pragma unroll
        for (int i = 0; i < 4; ++i) {
            const int idx = tid + i * 256;
            const int r = idx >> 4;
            const int cv = idx & 15;
            F4 k4; k4.v = *(const float4*)(K + base + (size_t)(k0 + r) * D_MODEL + cv * 4);
            Kt[cv * 4 + 0][r] = k4.f[0];
            Kt[cv * 4 + 1][r] = k4.f[1];
            Kt[cv * 4 + 2][r] = k4.f[2];
            Kt[cv * 4 + 3][r] = k4.f[3];
            float4 v4 = *(const float4*)(V + base + (size_t)(k0 + r) * D_MODEL + cv * 4);
            *(float4*)&Vs[r][cv * 4] = v4;
        }
        __syncthreads();

        float s[4][4] = {};
#pragma unroll
        for (int d = 0; d < DK; ++d) {
            F4 qv, kv;
            qv.v = *(const float4*)&Qt[d][ty * 4];
            kv.v = *(const float4*)&Kt[d][tx * 4];
#pragma unroll
            for (int i = 0; i < 4; ++i)
#pragma unroll
                for (int j = 0; j < 4; ++j)
                    s[i][j] = fmaf(qv.f[i], kv.f[j], s[i][j]);
        }

        int mk[4];
#pragma unroll
        for (int j = 0; j < 4; ++j) mk[j] = mrow[k0 + tx * 4 + j];
#pragma unroll
        for (int i = 0; i < 4; ++i)
#pragma unroll
            for (int j = 0; j < 4; ++j)
                if (mk[j] == 0) s[i][j] = NEGINF;

#pragma unroll
        for (int i = 0; i < 4; ++i) {
            float rm = fmaxf(fmaxf(s[i][0], s[i][1]), fmaxf(s[i][2], s[i][3]));
            rm = fmaxf(rm, __shfl_xor(rm, 1));
            rm = fmaxf(rm, __shfl_xor(rm, 2));
            rm = fmaxf(rm, __shfl_xor(rm, 4));
            rm = fmaxf(rm, __shfl_xor(rm, 8));
            const float mn = fmaxf(m_run[i], rm);
            const float sc = __expf(m_run[i] - mn);
            F4 p;
#pragma unroll
            for (int j = 0; j < 4; ++j) p.f[j] = __expf(s[i][j] - mn);
            float rs = p.f[0] + p.f[1] + p.f[2] + p.f[3];
            rs += __shfl_xor(rs, 1);
            rs += __shfl_xor(rs, 2);
            rs += __shfl_xor(rs, 4);
            rs += __shfl_xor(rs, 8);
            l_run[i] = l_run[i] * sc + rs;
            m_run[i] = mn;
#pragma unroll
            for (int j = 0; j < 4; ++j) oa[i][j] *= sc;
            *(float4*)&Ps[ty * 4 + i][tx * 4] = p.v;
        }
        __syncthreads();

#pragma unroll
        for (int kk = 0; kk < 64; kk += 4) {
            F4 p0, p1, p2, p3, v0, v1, v2, v3;
            p0.v = *(const float4*)&Ps[ty * 4 + 0][kk];
            p1.v = *(const float4*)&Ps[ty * 4 + 1][kk];
            p2.v = *(const float4*)&Ps[ty * 4 + 2][kk];
            p3.v = *(const float4*)&Ps[ty * 4 + 3][kk];
            v0.v = *(const float4*)&Vs[kk + 0][tx * 4];
            v1.v = *(const float4*)&Vs[kk + 1][tx * 4];
            v2.v = *(const float4*)&Vs[kk + 2][tx * 4];
            v3.v = *(const float4*)&Vs[kk + 3][tx * 4];
            F4 pr[4] = {p0, p1, p2, p3};
#pragma unroll
            for (int i = 0; i < 4; ++i)
#pragma unroll
                for (int j = 0; j < 4; ++j) {
                    float t = fmaf(pr[i].f[0], v0.f[j], oa[i][j]);
                    t = fmaf(pr[i].f[1], v1.f[j], t);
                    t = fmaf(pr[i].f[2], v2.f[j], t);
                    oa[i][j] = fmaf(pr[i].f[3], v3.f[j], t);
                }
        }
    }

#pragma unroll
    for (int i = 0; i < 4; ++i) {
        const float invl = 1.0f / l_run[i];
        ushort4 o;
        o.x = f2bf(oa[i][0] * invl);
        o.y = f2bf(oa[i][1] * invl);
        o.z = f2bf(oa[i][2] * invl);
        o.w = f2bf(oa[i][3] * invl);
        *(ushort4*)(O + base + (size_t)(q0 + ty * 4 + i) * D_MODEL + tx * 4) = o;
    }
}

// ---------------------------------------------------------------------------
extern "C" void kernel_launch(void* const* d_in, const int* in_sizes, int n_in,
                              void* d_out, int out_size, void* d_ws, size_t ws_size,
                              hipStream_t stream) {
    const float* x   = (const float*)d_in[0];
    const int*   msk = (const int*)d_in[1];
    const float* Wq  = (const float*)d_in[2];
    const float* bq  = (const float*)d_in[3];
    const float* Wk  = (const float*)d_in[4];
    const float* bk  = (const float*)d_in[5];
    const float* Wv  = (const float*)d_in[6];
    const float* bv  = (const float*)d_in[7];
    const float* Wo  = (const float*)d_in[8];
    const float* bo  = (const float*)d_in[9];
    const float* W1  = (const float*)d_in[10];
    const float* b1  = (const float*)d_in[11];
    const float* W2  = (const float*)d_in[12];
    const float* b2  = (const float*)d_in[13];
    const float* g1  = (const float*)d_in[14];
    const float* be1 = (const float*)d_in[15];
    const float* g2  = (const float*)d_in[16];
    const float* be2 = (const float*)d_in[17];
    float* out = (float*)d_out;

    char* w = (char*)d_ws;
    unsigned short* h_bf  = (unsigned short*)w;  w += (size_t)ROWS * D_MODEL * 2;  // 8 MB
    float* qb  = (float*)w;                      w += (size_t)ROWS * D_MODEL * 4;  // 16 MB
    float* kb  = (float*)w;                      w += (size_t)ROWS * D_MODEL * 4;
    float* vb  = (float*)w;                      w += (size_t)ROWS * D_MODEL * 4;
    unsigned short* ctx_bf = (unsigned short*)w; w += (size_t)ROWS * D_MODEL * 2;
    float* xat = (float*)w;                      w += (size_t)ROWS * D_MODEL * 4;
    unsigned short* h2_bf  = (unsigned short*)w; w += (size_t)ROWS * D_MODEL * 2;
    unsigned short* ff1_bf = (unsigned short*)w; w += (size_t)ROWS * D_FF * 2;     // 32 MB
    unsigned short* Wq_bf  = (unsigned short*)w; w += (size_t)D_MODEL * D_MODEL * 2;
    unsigned short* Wk_bf  = (unsigned short*)w; w += (size_t)D_MODEL * D_MODEL * 2;
    unsigned short* Wv_bf  = (unsigned short*)w; w += (size_t)D_MODEL * D_MODEL * 2;
    unsigned short* Wo_bf  = (unsigned short*)w; w += (size_t)D_MODEL * D_MODEL * 2;
    unsigned short* W1_bf  = (unsigned short*)w; w += (size_t)D_FF * D_MODEL * 2;
    unsigned short* W2_bf  = (unsigned short*)w; w += (size_t)D_FF * D_MODEL * 2;

    const dim3 blk(256);
    const int nD = D_MODEL * D_MODEL / 4;   // float4 groups
    const int nF = D_FF * D_MODEL / 4;
    cast_bf16_kernel<<<(nD + 255) / 256, blk, 0, stream>>>(Wq, Wq_bf, nD);
    cast_bf16_kernel<<<(nD + 255) / 256, blk, 0, stream>>>(Wk, Wk_bf, nD);
    cast_bf16_kernel<<<(nD + 255) / 256, blk, 0, stream>>>(Wv, Wv_bf, nD);
    cast_bf16_kernel<<<(nD + 255) / 256, blk, 0, stream>>>(Wo, Wo_bf, nD);
    cast_bf16_kernel<<<(nF + 255) / 256, blk, 0, stream>>>(W1, W1_bf, nF);
    cast_bf16_kernel<<<(nF + 255) / 256, blk, 0, stream>>>(W2, W2_bf, nF);

    ln_bf16_kernel<<<ROWS, blk, 0, stream>>>(x, g1, be1, h_bf);

    const dim3 gD(D_MODEL / 128, ROWS / 128);   // 8 x 32
    const dim3 gF(D_FF / 128, ROWS / 128);      // 32 x 32

    gemm_bf16<false, false, false><<<gD, blk, 0, stream>>>(h_bf, Wq_bf, bq, nullptr, qb, ROWS, D_MODEL, D_MODEL);
    gemm_bf16<false, false, false><<<gD, blk, 0, stream>>>(h_bf, Wk_bf, bk, nullptr, kb, ROWS, D_MODEL, D_MODEL);
    gemm_bf16<false, false, false><<<gD, blk, 0, stream>>>(h_bf, Wv_bf, bv, nullptr, vb, ROWS, D_MODEL, D_MODEL);

    attn_kernel<<<dim3(SS / 64, BB * N_HEADS), blk, 0, stream>>>(qb, kb, vb, msk, ctx_bf);

    gemm_bf16<false, true, false><<<gD, blk, 0, stream>>>(ctx_bf, Wo_bf, bo, x, xat, ROWS, D_MODEL, D_MODEL);

    ln_bf16_kernel<<<ROWS, blk, 0, stream>>>(xat, g2, be2, h2_bf);

    gemm_bf16<true, false, true><<<gF, blk, 0, stream>>>(h2_bf, W1_bf, b1, nullptr, ff1_bf, ROWS, D_FF, D_MODEL);
    gemm_bf16<false, true, false><<<gD, blk, 0, stream>>>(ff1_bf, W2_bf, b2, xat, out, ROWS, D_MODEL, D_FF);
}

// Round 3
// 527.303 us; speedup vs baseline: 4.4621x; 2.2365x over previous
//
#include <hip/hip_runtime.h>
#include <math.h>

#define D_MODEL 1024
#define N_HEADS 16
#define DK      64
#define D_FF    4096
#define BB      2
#define SS      2048
#define ROWS    (BB * SS)          // 4096 token rows
#define EPS     1e-8f
#define NEGINF  -1e9f

union F4 { float4 v; float f[4]; };

typedef __attribute__((ext_vector_type(8))) short   bf16x8;  // 8 bf16 in 4 VGPRs
typedef __attribute__((ext_vector_type(4))) float   f32x4;

// round-to-nearest-even fp32 -> bf16
__device__ __forceinline__ unsigned short f2bf(float f) {
    union { float f; unsigned u; } a; a.f = f;
    unsigned r = a.u + 0x7FFFu + ((a.u >> 16) & 1u);
    return (unsigned short)(r >> 16);
}

// async global->LDS, 16 bytes per lane. LDS dest: wave-uniform base + lane*16.
__device__ __forceinline__ void gload16(const void* g, void* l) {
    __builtin_amdgcn_global_load_lds(
        (const __attribute__((address_space(1))) unsigned int*)g,
        (__attribute__((address_space(3))) unsigned int*)l, 16, 0, 0);
}

// ---------------------------------------------------------------------------
// LayerNorm -> bf16. One block (256 thr) per row. torch semantics:
// mean, unbiased std (ddof=1), eps added to std.
// ---------------------------------------------------------------------------
__global__ __launch_bounds__(256) void ln_bf16_kernel(const float* __restrict__ x,
                                                      const float* __restrict__ g,
                                                      const float* __restrict__ be,
                                                      unsigned short* __restrict__ out) {
    __shared__ float sm[8];
    const int row = blockIdx.x;
    const float4* xr = (const float4*)(x + (size_t)row * D_MODEL);
    float4 v = xr[threadIdx.x];

    float s = v.x + v.y + v.z + v.w;
#pragma unroll
    for (int o = 32; o; o >>= 1) s += __shfl_xor(s, o);
    const int wid = threadIdx.x >> 6, lane = threadIdx.x & 63;
    if (lane == 0) sm[wid] = s;
    __syncthreads();
    const float mean = (sm[0] + sm[1] + sm[2] + sm[3]) * (1.0f / D_MODEL);

    const float dx = v.x - mean, dy = v.y - mean, dz = v.z - mean, dw = v.w - mean;
    float sq = dx * dx + dy * dy + dz * dz + dw * dw;
#pragma unroll
    for (int o = 32; o; o >>= 1) sq += __shfl_xor(sq, o);
    if (lane == 0) sm[4 + wid] = sq;
    __syncthreads();
    const float var = (sm[4] + sm[5] + sm[6] + sm[7]) * (1.0f / (D_MODEL - 1));
    const float inv = 1.0f / (sqrtf(var) + EPS);
    const float g0 = g[0], b0 = be[0];

    ushort4 o4;
    o4.x = f2bf(g0 * dx * inv + b0);
    o4.y = f2bf(g0 * dy * inv + b0);
    o4.z = f2bf(g0 * dz * inv + b0);
    o4.w = f2bf(g0 * dw * inv + b0);
    ((ushort4*)(out + (size_t)row * D_MODEL))[threadIdx.x] = o4;
}

// ---------------------------------------------------------------------------
// fp32 -> bf16 cast (weights).
// ---------------------------------------------------------------------------
__global__ __launch_bounds__(256) void cast_bf16_kernel(const float* __restrict__ in,
                                                        unsigned short* __restrict__ out,
                                                        int n4) {
    const int i = blockIdx.x * 256 + threadIdx.x;
    if (i < n4) {
        float4 v = ((const float4*)in)[i];
        ushort4 o = { f2bf(v.x), f2bf(v.y), f2bf(v.z), f2bf(v.w) };
        ((ushort4*)out)[i] = o;
    }
}

// ---------------------------------------------------------------------------
// bf16 MFMA GEMM (m97 structure): C[M,N] = A[M,K] @ B[N,K]^T + bias
// 128x128 tile, BK=32, 4 waves 2x2, 4x4 fragments of 16x16x32 per wave.
// BROW: bias indexed by output row (for the V^T GEMM). scale applied after
// bias (used to fold 1/sqrt(dk) into Q).
// ---------------------------------------------------------------------------
template <bool RELU, bool RES, bool OUTBF, bool BROW>
__global__ __launch_bounds__(256) void gemm_bf16(const unsigned short* __restrict__ A,
                                                 const unsigned short* __restrict__ B,
                                                 const float* __restrict__ bias,
                                                 const float* __restrict__ res,
                                                 void* __restrict__ Cout,
                                                 int M, int N, int K, float scale) {
    __shared__ unsigned short As[128 * 32];   // [row][k] linear, row = 64 B
    __shared__ unsigned short Bs[128 * 32];

    const int bm = blockIdx.y * 128;
    const int bn = blockIdx.x * 128;
    const int tid  = threadIdx.x;
    const int lane = tid & 63;
    const int wv   = tid >> 6;          // 0..3
    const int wr   = wv >> 1;           // wave row (0..1)
    const int wc   = wv & 1;            // wave col (0..1)
    const int lr   = lane & 15;
    const int lq   = lane >> 4;

    f32x4 acc[4][4];
#pragma unroll
    for (int m = 0; m < 4; ++m)
#pragma unroll
        for (int n = 0; n < 4; ++n)
            acc[m][n] = (f32x4){0.f, 0.f, 0.f, 0.f};

    const int srow = wv * 32 + (lane >> 2);
    const int scol = (lane & 3) * 8;

    for (int k0 = 0; k0 < K; k0 += 32) {
        __syncthreads();
        gload16(A + (size_t)(bm + srow) * K + k0 + scol,        &As[(wv * 32) * 32]);
        gload16(A + (size_t)(bm + srow + 16) * K + k0 + scol,   &As[(wv * 32 + 16) * 32]);
        gload16(B + (size_t)(bn + srow) * K + k0 + scol,        &Bs[(wv * 32) * 32]);
        gload16(B + (size_t)(bn + srow + 16) * K + k0 + scol,   &Bs[(wv * 32 + 16) * 32]);
        __syncthreads();

        bf16x8 af[4], bf[4];
#pragma unroll
        for (int m = 0; m < 4; ++m)
            af[m] = *(const bf16x8*)&As[(wr * 64 + m * 16 + lr) * 32 + lq * 8];
#pragma unroll
        for (int n = 0; n < 4; ++n)
            bf[n] = *(const bf16x8*)&Bs[(wc * 64 + n * 16 + lr) * 32 + lq * 8];

#pragma unroll
        for (int m = 0; m < 4; ++m)
#pragma unroll
            for (int n = 0; n < 4; ++n)
                acc[m][n] = __builtin_amdgcn_mfma_f32_16x16x32_bf16(af[m], bf[n], acc[m][n], 0, 0, 0);
    }

    // epilogue: C/D layout col = lane&15, row = (lane>>4)*4 + reg
#pragma unroll
    for (int n = 0; n < 4; ++n) {
        const int col = bn + wc * 64 + n * 16 + lr;
        const float bcol = BROW ? 0.0f : bias[col];
#pragma unroll
        for (int m = 0; m < 4; ++m) {
#pragma unroll
            for (int r = 0; r < 4; ++r) {
                const int row = bm + wr * 64 + m * 16 + lq * 4 + r;
                float v = acc[m][n][r] + (BROW ? bias[row] : bcol);
                v *= scale;
                if (RELU) v = fmaxf(v, 0.0f);
                if (RES)  v += res[(size_t)row * N + col];
                if (OUTBF) ((unsigned short*)Cout)[(size_t)row * N + col] = f2bf(v);
                else       ((float*)Cout)[(size_t)row * N + col] = v;
            }
        }
    }
}

// ---------------------------------------------------------------------------
// bf16 MFMA flash attention. Grid (bh, qt): x = b*16+h (32, gives XCD/L2
// head affinity since 32%8==0), y = 64-row query tile (32).
// Block: 256 thr = 4 waves; wave w owns q-rows [q0+w*16, q0+w*16+16).
// Q pre-scaled by 1/8 in the Q-GEMM. V consumed transposed (Vt[d][token]).
// S-fragment layout per wave: q = w*16 + lq*4 + r, k = n*16 + lr
//   -> online softmax is wave-local: in-lane over n + shfl_xor(1,2,4,8).
// ---------------------------------------------------------------------------
__global__ __launch_bounds__(256) void attn_mfma(const unsigned short* __restrict__ Q,
                                                 const unsigned short* __restrict__ K,
                                                 const unsigned short* __restrict__ Vt,
                                                 const int* __restrict__ mask,
                                                 unsigned short* __restrict__ O) {
    __shared__ unsigned short Ks[64][68];   // [k][d], stride 136B
    __shared__ unsigned short Vs[64][68];   // [d][k]
    __shared__ unsigned short Ps[64][68];   // [q][k], wave-private rows

    const int bh = blockIdx.x;
    const int qt = blockIdx.y;
    const int b = bh >> 4, h = bh & 15;
    const int q0 = qt * 64;
    const int tid = threadIdx.x;
    const int w = tid >> 6;
    const int lane = tid & 63;
    const int lr = lane & 15, lq = lane >> 4;

    const size_t qkbase = (size_t)b * SS * D_MODEL + (size_t)h * DK;
    const int tok0 = b * SS;
    const int* mrow = mask + (size_t)b * SS;

    // Q fragments in registers: rows q0 + w*16 + lr
    bf16x8 qf[2];
    {
        const unsigned short* qp = Q + qkbase + (size_t)(q0 + w * 16 + lr) * D_MODEL;
        qf[0] = *(const bf16x8*)(qp);
        qf[1] = *(const bf16x8*)(qp + 32 + lq * 8 - lq * 8 + 32);  // placeholder fix below
    }
    // (correct per-fragment k offsets)
    {
        const unsigned short* qp = Q + qkbase + (size_t)(q0 + w * 16 + lr) * D_MODEL;
        qf[0] = *(const bf16x8*)(qp + 0 * 32 + lq * 8);
        qf[1] = *(const bf16x8*)(qp + 1 * 32 + lq * 8);
    }

    f32x4 acc_o[4];
#pragma unroll
    for (int n = 0; n < 4; ++n) acc_o[n] = (f32x4){0.f, 0.f, 0.f, 0.f};
    float m_run[4], l_run[4];
#pragma unroll
    for (int r = 0; r < 4; ++r) { m_run[r] = -1e30f; l_run[r] = 0.f; }

    for (int kt = 0; kt < SS / 64; ++kt) {
        const int k0 = kt * 64;
        __syncthreads();   // prior-tile Ks/Vs reads complete
#pragma unroll
        for (int i = 0; i < 2; ++i) {
            const int c = tid + i * 256;        // 0..511
            const int r = c >> 3, ch = c & 7;   // row 0..63, 8-el chunk 0..7
            bf16x8 kv = *(const bf16x8*)(K + qkbase + (size_t)(k0 + r) * D_MODEL + ch * 8);
            *(bf16x8*)&Ks[r][ch * 8] = kv;
            bf16x8 vv = *(const bf16x8*)(Vt + (size_t)(h * DK + r) * ROWS + tok0 + k0 + ch * 8);
            *(bf16x8*)&Vs[r][ch * 8] = vv;
        }
        __syncthreads();

        // QK^T (Q already scaled by 1/8)
        f32x4 sa[4];
#pragma unroll
        for (int n = 0; n < 4; ++n) sa[n] = (f32x4){0.f, 0.f, 0.f, 0.f};
#pragma unroll
        for (int ks = 0; ks < 2; ++ks) {
#pragma unroll
            for (int n = 0; n < 4; ++n) {
                bf16x8 kf = *(const bf16x8*)&Ks[n * 16 + lr][ks * 32 + lq * 8];
                sa[n] = __builtin_amdgcn_mfma_f32_16x16x32_bf16(qf[ks], kf, sa[n], 0, 0, 0);
            }
        }

        // mask: column k0 + n*16 + lr, broadcast over the 4 rows
#pragma unroll
        for (int n = 0; n < 4; ++n) {
            if (mrow[k0 + n * 16 + lr] == 0) {
                sa[n][0] = NEGINF; sa[n][1] = NEGINF; sa[n][2] = NEGINF; sa[n][3] = NEGINF;
            }
        }

        // online softmax per q-row (r indexes rows lq*4+r)
#pragma unroll
        for (int r = 0; r < 4; ++r) {
            float rm = fmaxf(fmaxf(sa[0][r], sa[1][r]), fmaxf(sa[2][r], sa[3][r]));
            rm = fmaxf(rm, __shfl_xor(rm, 1));
            rm = fmaxf(rm, __shfl_xor(rm, 2));
            rm = fmaxf(rm, __shfl_xor(rm, 4));
            rm = fmaxf(rm, __shfl_xor(rm, 8));
            const float mn = fmaxf(m_run[r], rm);
            const float sc = __expf(m_run[r] - mn);
            m_run[r] = mn;
            float rs = 0.f;
#pragma unroll
            for (int n = 0; n < 4; ++n) {
                const float pv = __expf(sa[n][r] - mn);
                sa[n][r] = pv;
                rs += pv;
            }
            rs += __shfl_xor(rs, 1);
            rs += __shfl_xor(rs, 2);
            rs += __shfl_xor(rs, 4);
            rs += __shfl_xor(rs, 8);
            l_run[r] = l_run[r] * sc + rs;
#pragma unroll
            for (int n = 0; n < 4; ++n) acc_o[n][r] *= sc;
        }

        // P -> LDS (bf16), wave-private rows; no barrier needed
#pragma unroll
        for (int r = 0; r < 4; ++r)
#pragma unroll
            for (int n = 0; n < 4; ++n)
                Ps[w * 16 + lq * 4 + r][n * 16 + lr] = f2bf(sa[n][r]);

        // PV: O[q][d] += P[q][k] * Vt[d][k]
#pragma unroll
        for (int ks = 0; ks < 2; ++ks) {
            bf16x8 pa = *(const bf16x8*)&Ps[w * 16 + lr][ks * 32 + lq * 8];
#pragma unroll
            for (int n = 0; n < 4; ++n) {
                bf16x8 vf = *(const bf16x8*)&Vs[n * 16 + lr][ks * 32 + lq * 8];
                acc_o[n] = __builtin_amdgcn_mfma_f32_16x16x32_bf16(pa, vf, acc_o[n], 0, 0, 0);
            }
        }
    }

    // epilogue: q = q0 + w*16 + lq*4 + r, d = n*16 + lr
#pragma unroll
    for (int r = 0; r < 4; ++r) {
        const float invl = 1.0f / l_run[r];
        const size_t row = (size_t)(q0 + w * 16 + lq * 4 + r);
#pragma unroll
        for (int n = 0; n < 4; ++n)
            O[qkbase + row * D_MODEL + n * 16 + lr] = f2bf(acc_o[n][r] * invl);
    }
}

// ---------------------------------------------------------------------------
extern "C" void kernel_launch(void* const* d_in, const int* in_sizes, int n_in,
                              void* d_out, int out_size, void* d_ws, size_t ws_size,
                              hipStream_t stream) {
    const float* x   = (const float*)d_in[0];
    const int*   msk = (const int*)d_in[1];
    const float* Wq  = (const float*)d_in[2];
    const float* bq  = (const float*)d_in[3];
    const float* Wk  = (const float*)d_in[4];
    const float* bk  = (const float*)d_in[5];
    const float* Wv  = (const float*)d_in[6];
    const float* bv  = (const float*)d_in[7];
    const float* Wo  = (const float*)d_in[8];
    const float* bo  = (const float*)d_in[9];
    const float* W1  = (const float*)d_in[10];
    const float* b1  = (const float*)d_in[11];
    const float* W2  = (const float*)d_in[12];
    const float* b2  = (const float*)d_in[13];
    const float* g1  = (const float*)d_in[14];
    const float* be1 = (const float*)d_in[15];
    const float* g2  = (const float*)d_in[16];
    const float* be2 = (const float*)d_in[17];
    float* out = (float*)d_out;

    char* w = (char*)d_ws;
    unsigned short* h_bf   = (unsigned short*)w; w += (size_t)ROWS * D_MODEL * 2;
    unsigned short* qb_bf  = (unsigned short*)w; w += (size_t)ROWS * D_MODEL * 2;
    unsigned short* kb_bf  = (unsigned short*)w; w += (size_t)ROWS * D_MODEL * 2;
    unsigned short* vt_bf  = (unsigned short*)w; w += (size_t)ROWS * D_MODEL * 2;  // [1024][4096]
    unsigned short* ctx_bf = (unsigned short*)w; w += (size_t)ROWS * D_MODEL * 2;
    float* xat             = (float*)w;          w += (size_t)ROWS * D_MODEL * 4;
    unsigned short* h2_bf  = (unsigned short*)w; w += (size_t)ROWS * D_MODEL * 2;
    unsigned short* ff1_bf = (unsigned short*)w; w += (size_t)ROWS * D_FF * 2;
    unsigned short* Wq_bf  = (unsigned short*)w; w += (size_t)D_MODEL * D_MODEL * 2;
    unsigned short* Wk_bf  = (unsigned short*)w; w += (size_t)D_MODEL * D_MODEL * 2;
    unsigned short* Wv_bf  = (unsigned short*)w; w += (size_t)D_MODEL * D_MODEL * 2;
    unsigned short* Wo_bf  = (unsigned short*)w; w += (size_t)D_MODEL * D_MODEL * 2;
    unsigned short* W1_bf  = (unsigned short*)w; w += (size_t)D_FF * D_MODEL * 2;
    unsigned short* W2_bf  = (unsigned short*)w; w += (size_t)D_FF * D_MODEL * 2;

    const dim3 blk(256);
    const int nD = D_MODEL * D_MODEL / 4;
    const int nF = D_FF * D_MODEL / 4;
    cast_bf16_kernel<<<(nD + 255) / 256, blk, 0, stream>>>(Wq, Wq_bf, nD);
    cast_bf16_kernel<<<(nD + 255) / 256, blk, 0, stream>>>(Wk, Wk_bf, nD);
    cast_bf16_kernel<<<(nD + 255) / 256, blk, 0, stream>>>(Wv, Wv_bf, nD);
    cast_bf16_kernel<<<(nD + 255) / 256, blk, 0, stream>>>(Wo, Wo_bf, nD);
    cast_bf16_kernel<<<(nF + 255) / 256, blk, 0, stream>>>(W1, W1_bf, nF);
    cast_bf16_kernel<<<(nF + 255) / 256, blk, 0, stream>>>(W2, W2_bf, nF);

    ln_bf16_kernel<<<ROWS, blk, 0, stream>>>(x, g1, be1, h_bf);

    const dim3 gD(D_MODEL / 128, ROWS / 128);   // 8 x 32
    const dim3 gF(D_FF / 128, ROWS / 128);      // 32 x 32
    const dim3 gV(ROWS / 128, D_MODEL / 128);   // 32 x 8  (Vt: M=1024, N=4096)

    // Q (prescaled by 1/8), K: bf16 outputs
    gemm_bf16<false, false, true, false><<<gD, blk, 0, stream>>>(h_bf, Wq_bf, bq, nullptr, qb_bf, ROWS, D_MODEL, D_MODEL, 0.125f);
    gemm_bf16<false, false, true, false><<<gD, blk, 0, stream>>>(h_bf, Wk_bf, bk, nullptr, kb_bf, ROWS, D_MODEL, D_MODEL, 1.0f);
    // Vt[d][token] = Wv . h^T + bv[d]  (row-bias)
    gemm_bf16<false, false, true, true><<<gV, blk, 0, stream>>>(Wv_bf, h_bf, bv, nullptr, vt_bf, D_MODEL, ROWS, D_MODEL, 1.0f);

    attn_mfma<<<dim3(BB * N_HEADS, SS / 64), blk, 0, stream>>>(qb_bf, kb_bf, vt_bf, msk, ctx_bf);

    gemm_bf16<false, true, false, false><<<gD, blk, 0, stream>>>(ctx_bf, Wo_bf, bo, x, xat, ROWS, D_MODEL, D_MODEL, 1.0f);

    ln_bf16_kernel<<<ROWS, blk, 0, stream>>>(xat, g2, be2, h2_bf);

    gemm_bf16<true, false, true, false><<<gF, blk, 0, stream>>>(h2_bf, W1_bf, b1, nullptr, ff1_bf, ROWS, D_FF, D_MODEL, 1.0f);
    gemm_bf16<false, true, false, false><<<gD, blk, 0, stream>>>(ff1_bf, W2_bf, b2, xat, out, ROWS, D_MODEL, D_FF, 1.0f);
}

// Round 4
// 426.273 us; speedup vs baseline: 5.5197x; 1.2370x over previous
//
#include <hip/hip_runtime.h>
#include <math.h>

#define D_MODEL 1024
#define N_HEADS 16
#define DK      64
#define D_FF    4096
#define BB      2
#define SS      2048
#define ROWS    (BB * SS)
#define EPS     1e-8f
#define NEG     -1e9f
#define QSCALE  0.1803368801111f   // 0.125 * log2(e): softmax in exp2 domain

union F4 { float4 v; float f[4]; };

typedef __attribute__((ext_vector_type(8))) short   bf16x8;
typedef __attribute__((ext_vector_type(4))) float   f32x4;

__device__ __forceinline__ unsigned short f2bf(float f) {
    union { float f; unsigned u; } a; a.f = f;
    unsigned r = a.u + 0x7FFFu + ((a.u >> 16) & 1u);
    return (unsigned short)(r >> 16);
}

__device__ __forceinline__ float exp2_fast(float x) {   // 2^x via v_exp_f32
    float r;
    asm("v_exp_f32 %0, %1" : "=v"(r) : "v"(x));
    return r;
}

__device__ __forceinline__ unsigned cvt_pk_bf16(float lo, float hi) {
    unsigned r;
    asm("v_cvt_pk_bf16_f32 %0, %1, %2" : "=v"(r) : "v"(lo), "v"(hi));
    return r;
}

__device__ __forceinline__ void gload16(const void* g, void* l) {
    __builtin_amdgcn_global_load_lds(
        (const __attribute__((address_space(1))) unsigned int*)g,
        (__attribute__((address_space(3))) unsigned int*)l, 16, 0, 0);
}

// ---------------------------------------------------------------------------
// LayerNorm -> bf16 (torch semantics: mean, ddof=1 std, eps on std)
// ---------------------------------------------------------------------------
__global__ __launch_bounds__(256) void ln_bf16_kernel(const float* __restrict__ x,
                                                      const float* __restrict__ g,
                                                      const float* __restrict__ be,
                                                      unsigned short* __restrict__ out) {
    __shared__ float sm[8];
    const int row = blockIdx.x;
    float4 v = ((const float4*)(x + (size_t)row * D_MODEL))[threadIdx.x];

    float s = v.x + v.y + v.z + v.w;
#pragma unroll
    for (int o = 32; o; o >>= 1) s += __shfl_xor(s, o);
    const int wid = threadIdx.x >> 6, lane = threadIdx.x & 63;
    if (lane == 0) sm[wid] = s;
    __syncthreads();
    const float mean = (sm[0] + sm[1] + sm[2] + sm[3]) * (1.0f / D_MODEL);

    const float dx = v.x - mean, dy = v.y - mean, dz = v.z - mean, dw = v.w - mean;
    float sq = dx * dx + dy * dy + dz * dz + dw * dw;
#pragma unroll
    for (int o = 32; o; o >>= 1) sq += __shfl_xor(sq, o);
    if (lane == 0) sm[4 + wid] = sq;
    __syncthreads();
    const float var = (sm[4] + sm[5] + sm[6] + sm[7]) * (1.0f / (D_MODEL - 1));
    const float inv = 1.0f / (sqrtf(var) + EPS);
    const float g0 = g[0], b0 = be[0];

    ushort4 o4;
    o4.x = f2bf(g0 * dx * inv + b0);
    o4.y = f2bf(g0 * dy * inv + b0);
    o4.z = f2bf(g0 * dz * inv + b0);
    o4.w = f2bf(g0 * dw * inv + b0);
    ((ushort4*)(out + (size_t)row * D_MODEL))[threadIdx.x] = o4;
}

__global__ __launch_bounds__(256) void cast_bf16_kernel(const float* __restrict__ in,
                                                        unsigned short* __restrict__ out,
                                                        int n4) {
    const int i = blockIdx.x * 256 + threadIdx.x;
    if (i < n4) {
        float4 v = ((const float4*)in)[i];
        ushort4 o = { f2bf(v.x), f2bf(v.y), f2bf(v.z), f2bf(v.w) };
        ((ushort4*)out)[i] = o;
    }
}

// mask -> additive f32 bias (0 / -1e9) + per-64-key-tile "any zero" flags
__global__ __launch_bounds__(256) void mask_prep(const int* __restrict__ mask,
                                                 float* __restrict__ mbias,
                                                 int* __restrict__ tflag) {
    const int i = blockIdx.x * 256 + threadIdx.x;   // over B*S = 4096
    const int m = mask[i];
    mbias[i] = m ? 0.0f : NEG;
    unsigned long long z = __ballot(m == 0);
    if ((threadIdx.x & 63) == 0) tflag[i >> 6] = (z != 0ull) ? 1 : 0;
}

// ---------------------------------------------------------------------------
// bf16 MFMA GEMM core: C[M,N] = A[M,K] @ B[N,K]^T + bias, double-buffered
// LDS (2-phase pipeline: stage t+1 before computing t, one barrier/K-step).
// 128x128 tile, BK=32, 4 waves 2x2, 4x4 fragments of 16x16x32 per wave.
// ---------------------------------------------------------------------------
template <bool RELU, bool RES, bool OUTBF, bool BROW>
__device__ __forceinline__ void gemm_core(const unsigned short* __restrict__ A,
                                          const unsigned short* __restrict__ B,
                                          const float* __restrict__ bias,
                                          const float* __restrict__ res,
                                          void* __restrict__ Cout,
                                          int M, int N, int K, float scale,
                                          int bm, int bn,
                                          unsigned short* As, unsigned short* Bs) {
    const int tid  = threadIdx.x;
    const int lane = tid & 63;
    const int wv   = tid >> 6;
    const int wr   = wv >> 1, wc = wv & 1;
    const int lr   = lane & 15, lq = lane >> 4;

    f32x4 acc[4][4];
#pragma unroll
    for (int m = 0; m < 4; ++m)
#pragma unroll
        for (int n = 0; n < 4; ++n)
            acc[m][n] = (f32x4){0.f, 0.f, 0.f, 0.f};

    const int srow = wv * 32 + (lane >> 2);
    const int scol = (lane & 3) * 8;

    auto stage = [&](int buf, int k0) {
        unsigned short* ab = As + buf * 4096;
        unsigned short* bb = Bs + buf * 4096;
        gload16(A + (size_t)(bm + srow) * K + k0 + scol,      &ab[(wv * 32) * 32]);
        gload16(A + (size_t)(bm + srow + 16) * K + k0 + scol, &ab[(wv * 32 + 16) * 32]);
        gload16(B + (size_t)(bn + srow) * K + k0 + scol,      &bb[(wv * 32) * 32]);
        gload16(B + (size_t)(bn + srow + 16) * K + k0 + scol, &bb[(wv * 32 + 16) * 32]);
    };

    const int T = K >> 5;
    stage(0, 0);
    __syncthreads();                       // drain prologue (vmcnt(0) in barrier)

    for (int t = 0; t < T; ++t) {
        const int cur = t & 1;
        if (t + 1 < T) stage(cur ^ 1, (t + 1) << 5);   // prefetch next tile
        __builtin_amdgcn_sched_barrier(0);             // keep prefetch issued first

        const unsigned short* ab = As + cur * 4096;
        const unsigned short* bb = Bs + cur * 4096;
        bf16x8 af[4], bf[4];
#pragma unroll
        for (int m = 0; m < 4; ++m)
            af[m] = *(const bf16x8*)&ab[(wr * 64 + m * 16 + lr) * 32 + lq * 8];
#pragma unroll
        for (int n = 0; n < 4; ++n)
            bf[n] = *(const bf16x8*)&bb[(wc * 64 + n * 16 + lr) * 32 + lq * 8];

#pragma unroll
        for (int m = 0; m < 4; ++m)
#pragma unroll
            for (int n = 0; n < 4; ++n)
                acc[m][n] = __builtin_amdgcn_mfma_f32_16x16x32_bf16(af[m], bf[n], acc[m][n], 0, 0, 0);

        __syncthreads();   // drains prefetch vmcnt + guards buffer reuse
    }

#pragma unroll
    for (int n = 0; n < 4; ++n) {
        const int col = bn + wc * 64 + n * 16 + lr;
        const float bcol = BROW ? 0.0f : bias[col];
#pragma unroll
        for (int m = 0; m < 4; ++m) {
#pragma unroll
            for (int r = 0; r < 4; ++r) {
                const int row = bm + wr * 64 + m * 16 + lq * 4 + r;
                float v = acc[m][n][r] + (BROW ? bias[row] : bcol);
                v *= scale;
                if (RELU) v = fmaxf(v, 0.0f);
                if (RES)  v += res[(size_t)row * N + col];
                if (OUTBF) ((unsigned short*)Cout)[(size_t)row * N + col] = f2bf(v);
                else       ((float*)Cout)[(size_t)row * N + col] = v;
            }
        }
    }
}

template <bool RELU, bool RES, bool OUTBF, bool BROW>
__global__ __launch_bounds__(256) void gemm_bf16(const unsigned short* __restrict__ A,
                                                 const unsigned short* __restrict__ B,
                                                 const float* __restrict__ bias,
                                                 const float* __restrict__ res,
                                                 void* __restrict__ Cout,
                                                 int M, int N, int K, float scale) {
    __shared__ unsigned short As[2 * 4096];
    __shared__ unsigned short Bs[2 * 4096];
    gemm_core<RELU, RES, OUTBF, BROW>(A, B, bias, res, Cout, M, N, K, scale,
                                      blockIdx.y * 128, blockIdx.x * 128, As, Bs);
}

// Fused Q/K/V^T projections: 768 blocks (3/CU). op = blockIdx.x>>8.
__global__ __launch_bounds__(256) void qkv_fused(const unsigned short* __restrict__ h,
                                                 const unsigned short* __restrict__ Wq,
                                                 const unsigned short* __restrict__ Wk,
                                                 const unsigned short* __restrict__ Wv,
                                                 const float* __restrict__ bq,
                                                 const float* __restrict__ bk,
                                                 const float* __restrict__ bv,
                                                 unsigned short* __restrict__ qo,
                                                 unsigned short* __restrict__ ko,
                                                 unsigned short* __restrict__ vto) {
    __shared__ unsigned short As[2 * 4096];
    __shared__ unsigned short Bs[2 * 4096];
    const int id = blockIdx.x;
    const int op = id >> 8;
    const int t  = id & 255;
    if (op == 0) {
        gemm_core<false, false, true, false>(h, Wq, bq, nullptr, qo,
            ROWS, D_MODEL, D_MODEL, QSCALE, (t >> 3) * 128, (t & 7) * 128, As, Bs);
    } else if (op == 1) {
        gemm_core<false, false, true, false>(h, Wk, bk, nullptr, ko,
            ROWS, D_MODEL, D_MODEL, 1.0f, (t >> 3) * 128, (t & 7) * 128, As, Bs);
    } else {
        // Vt[d][token] = Wv . h^T + bv[d]
        gemm_core<false, false, true, true>(Wv, h, bv, nullptr, vto,
            D_MODEL, ROWS, D_MODEL, 1.0f, (t >> 5) * 128, (t & 31) * 128, As, Bs);
    }
}

// ---------------------------------------------------------------------------
// bf16 MFMA flash attention, swapped-QK^T structure.
// Grid (bh=32, qt=32). 4 waves; wave w owns q-rows [q0+w*16, +16).
// Each lane owns ONE q-row (q=lane&15); S^T frags put 16 k-values in-lane.
// Q pre-scaled by 0.125*log2e -> softmax via v_exp_f32 (2^x).
// PV computes O^T = mfma(Vt-frag, P^T-frag). Async K/V prefetch (T14).
// ---------------------------------------------------------------------------
__global__ __launch_bounds__(256) void attn_mfma(const unsigned short* __restrict__ Q,
                                                 const unsigned short* __restrict__ K,
                                                 const unsigned short* __restrict__ Vt,
                                                 const float* __restrict__ mbias,
                                                 const int* __restrict__ tflag,
                                                 unsigned short* __restrict__ O) {
    __shared__ unsigned short Ks[64][68];   // [key][d]
    __shared__ unsigned short Vs[64][68];   // [d][key]
    __shared__ unsigned short Ps[64][68];   // [q][key], wave-private rows

    const int bh = blockIdx.x, qt = blockIdx.y;
    const int b = bh >> 4, h = bh & 15;
    const int q0 = qt * 64;
    const int tid = threadIdx.x;
    const int w = tid >> 6, lane = tid & 63;
    const int lr = lane & 15, lq = lane >> 4;

    const size_t qkbase = (size_t)b * SS * D_MODEL + (size_t)h * DK;
    const int tok0 = b * SS;
    const float* mb = mbias + (size_t)b * SS;
    const int* tf = tflag + b * (SS / 64);

    // Q as B-fragments (col = q = lr, k-chunk = lq*8)
    const unsigned short* qp = Q + qkbase + (size_t)(q0 + w * 16 + lr) * D_MODEL;
    const bf16x8 qf0 = *(const bf16x8*)(qp + lq * 8);
    const bf16x8 qf1 = *(const bf16x8*)(qp + 32 + lq * 8);

    // staging: thread covers rows sr, sr+32; 8-elem chunk sch
    const int sr = tid >> 3, sch = tid & 7;
    bf16x8 kreg0, kreg1, vreg0, vreg1;
    {
        const unsigned short* kp = K + qkbase + (size_t)sr * D_MODEL + sch * 8;
        kreg0 = *(const bf16x8*)(kp);
        kreg1 = *(const bf16x8*)(kp + 32 * D_MODEL);
        const unsigned short* vp = Vt + (size_t)(h * DK + sr) * ROWS + tok0 + sch * 8;
        vreg0 = *(const bf16x8*)(vp);
        vreg1 = *(const bf16x8*)(vp + 32 * ROWS);
    }

    f32x4 acc_o[4];
#pragma unroll
    for (int n = 0; n < 4; ++n) acc_o[n] = (f32x4){0.f, 0.f, 0.f, 0.f};
    float m_run = -1e30f, l_run = 0.0f;

    for (int kt = 0; kt < SS / 64; ++kt) {
        __syncthreads();          // previous tile's LDS reads complete
        *(bf16x8*)&Ks[sr][sch * 8]      = kreg0;
        *(bf16x8*)&Ks[sr + 32][sch * 8] = kreg1;
        *(bf16x8*)&Vs[sr][sch * 8]      = vreg0;
        *(bf16x8*)&Vs[sr + 32][sch * 8] = vreg1;
        __syncthreads();          // staged

        if (kt + 1 < SS / 64) {   // async prefetch next K/V tile into regs
            const int k1 = (kt + 1) * 64;
            const unsigned short* kp = K + qkbase + (size_t)(k1 + sr) * D_MODEL + sch * 8;
            kreg0 = *(const bf16x8*)(kp);
            kreg1 = *(const bf16x8*)(kp + 32 * D_MODEL);
            const unsigned short* vp = Vt + (size_t)(h * DK + sr) * ROWS + tok0 + k1 + sch * 8;
            vreg0 = *(const bf16x8*)(vp);
            vreg1 = *(const bf16x8*)(vp + 32 * ROWS);
        }

        // S^T = mfma(K, Q): lane holds q=lr; keys k = n*16 + lq*4 + r
        f32x4 sa[4];
#pragma unroll
        for (int n = 0; n < 4; ++n) sa[n] = (f32x4){0.f, 0.f, 0.f, 0.f};
#pragma unroll
        for (int n = 0; n < 4; ++n) {
            bf16x8 kf0 = *(const bf16x8*)&Ks[n * 16 + lr][lq * 8];
            bf16x8 kf1 = *(const bf16x8*)&Ks[n * 16 + lr][32 + lq * 8];
            sa[n] = __builtin_amdgcn_mfma_f32_16x16x32_bf16(kf0, qf0, sa[n], 0, 0, 0);
            sa[n] = __builtin_amdgcn_mfma_f32_16x16x32_bf16(kf1, qf1, sa[n], 0, 0, 0);
        }

        // additive mask bias (uniform-gated; all-ones mask skips entirely)
        if (tf[kt]) {
#pragma unroll
            for (int n = 0; n < 4; ++n) {
                F4 m4; m4.v = *(const float4*)&mb[kt * 64 + n * 16 + lq * 4];
#pragma unroll
                for (int r = 0; r < 4; ++r) sa[n][r] += m4.f[r];
            }
        }

        // online softmax; per-lane scalars (q = lr)
        float pmax = sa[0][0];
#pragma unroll
        for (int n = 0; n < 4; ++n)
#pragma unroll
            for (int r = 0; r < 4; ++r) pmax = fmaxf(pmax, sa[n][r]);
        pmax = fmaxf(pmax, __shfl_xor(pmax, 16));
        pmax = fmaxf(pmax, __shfl_xor(pmax, 32));
        const float mn = fmaxf(m_run, pmax);
        const float sc = exp2_fast(m_run - mn);
        m_run = mn;
        float rs = 0.0f;
#pragma unroll
        for (int n = 0; n < 4; ++n)
#pragma unroll
            for (int r = 0; r < 4; ++r) {
                const float p = exp2_fast(sa[n][r] - mn);
                sa[n][r] = p;
                rs += p;
            }
        rs += __shfl_xor(rs, 16);
        rs += __shfl_xor(rs, 32);
        l_run = l_run * sc + rs;
#pragma unroll
        for (int n = 0; n < 4; ++n) {
            acc_o[n][0] *= sc; acc_o[n][1] *= sc; acc_o[n][2] *= sc; acc_o[n][3] *= sc;
        }

        // pack P (bf16) -> LDS wave-private rows: row q, cols n*16+lq*4..+3
#pragma unroll
        for (int n = 0; n < 4; ++n) {
            uint2 u;
            u.x = cvt_pk_bf16(sa[n][0], sa[n][1]);
            u.y = cvt_pk_bf16(sa[n][2], sa[n][3]);
            *(uint2*)&Ps[w * 16 + lr][n * 16 + lq * 4] = u;
        }

        // PV: O^T[d][q] += Vt[d][k] * P^T[k][q]
#pragma unroll
        for (int c = 0; c < 2; ++c) {
            bf16x8 pf = *(const bf16x8*)&Ps[w * 16 + lr][c * 32 + lq * 8];
#pragma unroll
            for (int n = 0; n < 4; ++n) {
                bf16x8 vf = *(const bf16x8*)&Vs[n * 16 + lr][c * 32 + lq * 8];
                acc_o[n] = __builtin_amdgcn_mfma_f32_16x16x32_bf16(vf, pf, acc_o[n], 0, 0, 0);
            }
        }
    }

    // epilogue: lane's q = lr; d = n*16 + lq*4 + r (4 contiguous -> ushort4)
    const float invl = 1.0f / l_run;
    unsigned short* orow = O + qkbase + (size_t)(q0 + w * 16 + lr) * D_MODEL;
#pragma unroll
    for (int n = 0; n < 4; ++n) {
        ushort4 o;
        o.x = f2bf(acc_o[n][0] * invl);
        o.y = f2bf(acc_o[n][1] * invl);
        o.z = f2bf(acc_o[n][2] * invl);
        o.w = f2bf(acc_o[n][3] * invl);
        *(ushort4*)(orow + n * 16 + lq * 4) = o;
    }
}

// ---------------------------------------------------------------------------
extern "C" void kernel_launch(void* const* d_in, const int* in_sizes, int n_in,
                              void* d_out, int out_size, void* d_ws, size_t ws_size,
                              hipStream_t stream) {
    const float* x   = (const float*)d_in[0];
    const int*   msk = (const int*)d_in[1];
    const float* Wq  = (const float*)d_in[2];
    const float* bq  = (const float*)d_in[3];
    const float* Wk  = (const float*)d_in[4];
    const float* bk  = (const float*)d_in[5];
    const float* Wv  = (const float*)d_in[6];
    const float* bv  = (const float*)d_in[7];
    const float* Wo  = (const float*)d_in[8];
    const float* bo  = (const float*)d_in[9];
    const float* W1  = (const float*)d_in[10];
    const float* b1  = (const float*)d_in[11];
    const float* W2  = (const float*)d_in[12];
    const float* b2  = (const float*)d_in[13];
    const float* g1  = (const float*)d_in[14];
    const float* be1 = (const float*)d_in[15];
    const float* g2  = (const float*)d_in[16];
    const float* be2 = (const float*)d_in[17];
    float* out = (float*)d_out;

    char* w = (char*)d_ws;
    unsigned short* h_bf   = (unsigned short*)w; w += (size_t)ROWS * D_MODEL * 2;
    unsigned short* qb_bf  = (unsigned short*)w; w += (size_t)ROWS * D_MODEL * 2;
    unsigned short* kb_bf  = (unsigned short*)w; w += (size_t)ROWS * D_MODEL * 2;
    unsigned short* vt_bf  = (unsigned short*)w; w += (size_t)ROWS * D_MODEL * 2;
    unsigned short* ctx_bf = (unsigned short*)w; w += (size_t)ROWS * D_MODEL * 2;
    float* xat             = (float*)w;          w += (size_t)ROWS * D_MODEL * 4;
    unsigned short* h2_bf  = (unsigned short*)w; w += (size_t)ROWS * D_MODEL * 2;
    unsigned short* ff1_bf = (unsigned short*)w; w += (size_t)ROWS * D_FF * 2;
    unsigned short* Wq_bf  = (unsigned short*)w; w += (size_t)D_MODEL * D_MODEL * 2;
    unsigned short* Wk_bf  = (unsigned short*)w; w += (size_t)D_MODEL * D_MODEL * 2;
    unsigned short* Wv_bf  = (unsigned short*)w; w += (size_t)D_MODEL * D_MODEL * 2;
    unsigned short* Wo_bf  = (unsigned short*)w; w += (size_t)D_MODEL * D_MODEL * 2;
    unsigned short* W1_bf  = (unsigned short*)w; w += (size_t)D_FF * D_MODEL * 2;
    unsigned short* W2_bf  = (unsigned short*)w; w += (size_t)D_FF * D_MODEL * 2;
    float* mbias           = (float*)w;          w += (size_t)ROWS * 4;
    int* tflag             = (int*)w;            w += (size_t)(BB * SS / 64) * 4;

    const dim3 blk(256);
    const int nD = D_MODEL * D_MODEL / 4;
    const int nF = D_FF * D_MODEL / 4;
    cast_bf16_kernel<<<(nD + 255) / 256, blk, 0, stream>>>(Wq, Wq_bf, nD);
    cast_bf16_kernel<<<(nD + 255) / 256, blk, 0, stream>>>(Wk, Wk_bf, nD);
    cast_bf16_kernel<<<(nD + 255) / 256, blk, 0, stream>>>(Wv, Wv_bf, nD);
    cast_bf16_kernel<<<(nD + 255) / 256, blk, 0, stream>>>(Wo, Wo_bf, nD);
    cast_bf16_kernel<<<(nF + 255) / 256, blk, 0, stream>>>(W1, W1_bf, nF);
    cast_bf16_kernel<<<(nF + 255) / 256, blk, 0, stream>>>(W2, W2_bf, nF);
    mask_prep<<<ROWS / 256, blk, 0, stream>>>(msk, mbias, tflag);

    ln_bf16_kernel<<<ROWS, blk, 0, stream>>>(x, g1, be1, h_bf);

    qkv_fused<<<768, blk, 0, stream>>>(h_bf, Wq_bf, Wk_bf, Wv_bf, bq, bk, bv,
                                       qb_bf, kb_bf, vt_bf);

    attn_mfma<<<dim3(BB * N_HEADS, SS / 64), blk, 0, stream>>>(qb_bf, kb_bf, vt_bf,
                                                               mbias, tflag, ctx_bf);

    const dim3 gD(D_MODEL / 128, ROWS / 128);
    const dim3 gF(D_FF / 128, ROWS / 128);
    gemm_bf16<false, true, false, false><<<gD, blk, 0, stream>>>(ctx_bf, Wo_bf, bo, x, xat, ROWS, D_MODEL, D_MODEL, 1.0f);

    ln_bf16_kernel<<<ROWS, blk, 0, stream>>>(xat, g2, be2, h2_bf);

    gemm_bf16<true, false, true, false><<<gF, blk, 0, stream>>>(h2_bf, W1_bf, b1, nullptr, ff1_bf, ROWS, D_FF, D_MODEL, 1.0f);
    gemm_bf16<false, true, false, false><<<gD, blk, 0, stream>>>(ff1_bf, W2_bf, b2, xat, out, ROWS, D_MODEL, D_FF, 1.0f);
}

// Round 5
// 405.818 us; speedup vs baseline: 5.7979x; 1.0504x over previous
//
#include <hip/hip_runtime.h>
#include <math.h>

#define D_MODEL 1024
#define N_HEADS 16
#define DK      64
#define D_FF    4096
#define BB      2
#define SS      2048
#define ROWS    (BB * SS)
#define EPS     1e-8f
#define NEG     -1e9f
#define QSCALE  0.1803368801111f   // 0.125 * log2(e): softmax in exp2 domain
#define DEFER_THR 11.541560327f    // 8 * log2(e)

union F4 { float4 v; float f[4]; };

typedef __attribute__((ext_vector_type(8))) short   bf16x8;
typedef __attribute__((ext_vector_type(4))) float   f32x4;

__device__ __forceinline__ unsigned short f2bf(float f) {
    union { float f; unsigned u; } a; a.f = f;
    unsigned r = a.u + 0x7FFFu + ((a.u >> 16) & 1u);
    return (unsigned short)(r >> 16);
}

__device__ __forceinline__ float exp2_fast(float x) {
    float r;
    asm("v_exp_f32 %0, %1" : "=v"(r) : "v"(x));
    return r;
}

__device__ __forceinline__ unsigned cvt_pk_bf16(float lo, float hi) {
    unsigned r;
    asm("v_cvt_pk_bf16_f32 %0, %1, %2" : "=v"(r) : "v"(lo), "v"(hi));
    return r;
}

__device__ __forceinline__ void gload16(const void* g, void* l) {
    __builtin_amdgcn_global_load_lds(
        (const __attribute__((address_space(1))) unsigned int*)g,
        (__attribute__((address_space(3))) unsigned int*)l, 16, 0, 0);
}

// ---------------------------------------------------------------------------
// LayerNorm -> bf16 (torch semantics: mean, ddof=1 std, eps on std)
// ---------------------------------------------------------------------------
__global__ __launch_bounds__(256) void ln_bf16_kernel(const float* __restrict__ x,
                                                      const float* __restrict__ g,
                                                      const float* __restrict__ be,
                                                      unsigned short* __restrict__ out) {
    __shared__ float sm[8];
    const int row = blockIdx.x;
    float4 v = ((const float4*)(x + (size_t)row * D_MODEL))[threadIdx.x];

    float s = v.x + v.y + v.z + v.w;
#pragma unroll
    for (int o = 32; o; o >>= 1) s += __shfl_xor(s, o);
    const int wid = threadIdx.x >> 6, lane = threadIdx.x & 63;
    if (lane == 0) sm[wid] = s;
    __syncthreads();
    const float mean = (sm[0] + sm[1] + sm[2] + sm[3]) * (1.0f / D_MODEL);

    const float dx = v.x - mean, dy = v.y - mean, dz = v.z - mean, dw = v.w - mean;
    float sq = dx * dx + dy * dy + dz * dz + dw * dw;
#pragma unroll
    for (int o = 32; o; o >>= 1) sq += __shfl_xor(sq, o);
    if (lane == 0) sm[4 + wid] = sq;
    __syncthreads();
    const float var = (sm[4] + sm[5] + sm[6] + sm[7]) * (1.0f / (D_MODEL - 1));
    const float inv = 1.0f / (sqrtf(var) + EPS);
    const float g0 = g[0], b0 = be[0];

    ushort4 o4;
    o4.x = f2bf(g0 * dx * inv + b0);
    o4.y = f2bf(g0 * dy * inv + b0);
    o4.z = f2bf(g0 * dz * inv + b0);
    o4.w = f2bf(g0 * dw * inv + b0);
    ((ushort4*)(out + (size_t)row * D_MODEL))[threadIdx.x] = o4;
}

// ---------------------------------------------------------------------------
// Fused cast of ALL weights -> bf16 in one grid-stride launch.
// Layout: 4 x nD4 (Wq,Wk,Wv,Wo: 2^18 float4 each) then 2 x nF4 (W1,W2: 2^20).
// ---------------------------------------------------------------------------
__global__ __launch_bounds__(256) void cast_all(const float* __restrict__ s0,
                                                const float* __restrict__ s1,
                                                const float* __restrict__ s2,
                                                const float* __restrict__ s3,
                                                const float* __restrict__ s4,
                                                const float* __restrict__ s5,
                                                unsigned short* __restrict__ d0,
                                                unsigned short* __restrict__ d1,
                                                unsigned short* __restrict__ d2,
                                                unsigned short* __restrict__ d3,
                                                unsigned short* __restrict__ d4,
                                                unsigned short* __restrict__ d5) {
    const int ND4 = D_MODEL * D_MODEL / 4;   // 2^18
    const int NF4 = D_FF * D_MODEL / 4;      // 2^20
    const int total = 4 * ND4 + 2 * NF4;     // 3*2^20
    for (int i = blockIdx.x * 256 + threadIdx.x; i < total; i += gridDim.x * 256) {
        const float* s; unsigned short* d; int off;
        if (i < 4 * ND4) {
            const int w = i >> 18;
            off = i & (ND4 - 1);
            s = (w == 0) ? s0 : (w == 1) ? s1 : (w == 2) ? s2 : s3;
            d = (w == 0) ? d0 : (w == 1) ? d1 : (w == 2) ? d2 : d3;
        } else {
            const int j = i - 4 * ND4;
            const int w = j >> 20;
            off = j & (NF4 - 1);
            s = w ? s5 : s4;
            d = w ? d5 : d4;
        }
        float4 v = ((const float4*)s)[off];
        ushort4 o = { f2bf(v.x), f2bf(v.y), f2bf(v.z), f2bf(v.w) };
        ((ushort4*)d)[off] = o;
    }
}

// mask -> additive f32 bias (0 / -1e9, in log2 softmax domain scale by log2e)
__global__ __launch_bounds__(256) void mask_prep(const int* __restrict__ mask,
                                                 float* __restrict__ mbias,
                                                 int* __restrict__ tflag) {
    const int i = blockIdx.x * 256 + threadIdx.x;
    const int m = mask[i];
    mbias[i] = m ? 0.0f : NEG;
    unsigned long long z = __ballot(m == 0);
    if ((threadIdx.x & 63) == 0) tflag[i >> 6] = (z != 0ull) ? 1 : 0;
}

// ---------------------------------------------------------------------------
// bf16 MFMA GEMM core, 128x128 tile, BK=32, double-buffered LDS (2-phase).
// ---------------------------------------------------------------------------
template <bool RELU, bool RES, bool OUTBF, bool BROW>
__device__ __forceinline__ void gemm_core(const unsigned short* __restrict__ A,
                                          const unsigned short* __restrict__ B,
                                          const float* __restrict__ bias,
                                          const float* __restrict__ res,
                                          void* __restrict__ Cout,
                                          int M, int N, int K, float scale,
                                          int bm, int bn,
                                          unsigned short* As, unsigned short* Bs) {
    const int tid  = threadIdx.x;
    const int lane = tid & 63;
    const int wv   = tid >> 6;
    const int wr   = wv >> 1, wc = wv & 1;
    const int lr   = lane & 15, lq = lane >> 4;

    f32x4 acc[4][4];
#pragma unroll
    for (int m = 0; m < 4; ++m)
#pragma unroll
        for (int n = 0; n < 4; ++n)
            acc[m][n] = (f32x4){0.f, 0.f, 0.f, 0.f};

    const int srow = wv * 32 + (lane >> 2);
    const int scol = (lane & 3) * 8;

    auto stage = [&](int buf, int k0) {
        unsigned short* ab = As + buf * 4096;
        unsigned short* bb = Bs + buf * 4096;
        gload16(A + (size_t)(bm + srow) * K + k0 + scol,      &ab[(wv * 32) * 32]);
        gload16(A + (size_t)(bm + srow + 16) * K + k0 + scol, &ab[(wv * 32 + 16) * 32]);
        gload16(B + (size_t)(bn + srow) * K + k0 + scol,      &bb[(wv * 32) * 32]);
        gload16(B + (size_t)(bn + srow + 16) * K + k0 + scol, &bb[(wv * 32 + 16) * 32]);
    };

    const int T = K >> 5;
    stage(0, 0);
    __syncthreads();

    for (int t = 0; t < T; ++t) {
        const int cur = t & 1;
        if (t + 1 < T) stage(cur ^ 1, (t + 1) << 5);
        __builtin_amdgcn_sched_barrier(0);

        const unsigned short* ab = As + cur * 4096;
        const unsigned short* bb = Bs + cur * 4096;
        bf16x8 af[4], bf[4];
#pragma unroll
        for (int m = 0; m < 4; ++m)
            af[m] = *(const bf16x8*)&ab[(wr * 64 + m * 16 + lr) * 32 + lq * 8];
#pragma unroll
        for (int n = 0; n < 4; ++n)
            bf[n] = *(const bf16x8*)&bb[(wc * 64 + n * 16 + lr) * 32 + lq * 8];

#pragma unroll
        for (int m = 0; m < 4; ++m)
#pragma unroll
            for (int n = 0; n < 4; ++n)
                acc[m][n] = __builtin_amdgcn_mfma_f32_16x16x32_bf16(af[m], bf[n], acc[m][n], 0, 0, 0);

        __syncthreads();
    }

#pragma unroll
    for (int n = 0; n < 4; ++n) {
        const int col = bn + wc * 64 + n * 16 + lr;
        const float bcol = BROW ? 0.0f : bias[col];
#pragma unroll
        for (int m = 0; m < 4; ++m) {
#pragma unroll
            for (int r = 0; r < 4; ++r) {
                const int row = bm + wr * 64 + m * 16 + lq * 4 + r;
                float v = acc[m][n][r] + (BROW ? bias[row] : bcol);
                v *= scale;
                if (RELU) v = fmaxf(v, 0.0f);
                if (RES)  v += res[(size_t)row * N + col];
                if (OUTBF) ((unsigned short*)Cout)[(size_t)row * N + col] = f2bf(v);
                else       ((float*)Cout)[(size_t)row * N + col] = v;
            }
        }
    }
}

template <bool RELU, bool RES, bool OUTBF, bool BROW>
__global__ __launch_bounds__(256) void gemm_bf16(const unsigned short* __restrict__ A,
                                                 const unsigned short* __restrict__ B,
                                                 const float* __restrict__ bias,
                                                 const float* __restrict__ res,
                                                 void* __restrict__ Cout,
                                                 int M, int N, int K, float scale) {
    __shared__ unsigned short As[2 * 4096];
    __shared__ unsigned short Bs[2 * 4096];
    gemm_core<RELU, RES, OUTBF, BROW>(A, B, bias, res, Cout, M, N, K, scale,
                                      blockIdx.y * 128, blockIdx.x * 128, As, Bs);
}

// ---------------------------------------------------------------------------
// 128x64-tile GEMM for N=1024 outputs: grid 512 blocks = 2/CU so two blocks'
// phases overlap (the 1-block/CU launches had zero inter-block pipelining).
// 4 waves 2x2; wave = 64 rows x 32 cols = 4x2 fragments.
// ---------------------------------------------------------------------------
template <bool RELU, bool RES, bool OUTBF>
__global__ __launch_bounds__(256) void gemm_n64(const unsigned short* __restrict__ A,
                                                const unsigned short* __restrict__ B,
                                                const float* __restrict__ bias,
                                                const float* __restrict__ res,
                                                void* __restrict__ Cout,
                                                int M, int N, int K, float scale) {
    __shared__ unsigned short As[2 * 4096];   // 128 rows x 32
    __shared__ unsigned short Bs[2 * 2048];   // 64 rows x 32

    const int bm = blockIdx.y * 128;
    const int bn = blockIdx.x * 64;
    const int tid  = threadIdx.x;
    const int lane = tid & 63;
    const int wv   = tid >> 6;
    const int wr   = wv >> 1, wc = wv & 1;
    const int lr   = lane & 15, lq = lane >> 4;

    f32x4 acc[4][2];
#pragma unroll
    for (int m = 0; m < 4; ++m)
#pragma unroll
        for (int n = 0; n < 2; ++n)
            acc[m][n] = (f32x4){0.f, 0.f, 0.f, 0.f};

    const int sra = wv * 32 + (lane >> 2);
    const int srb = wv * 16 + (lane >> 2);
    const int scol = (lane & 3) * 8;

    auto stage = [&](int buf, int k0) {
        unsigned short* ab = As + buf * 4096;
        unsigned short* bb = Bs + buf * 2048;
        gload16(A + (size_t)(bm + sra) * K + k0 + scol,      &ab[(wv * 32) * 32]);
        gload16(A + (size_t)(bm + sra + 16) * K + k0 + scol, &ab[(wv * 32 + 16) * 32]);
        gload16(B + (size_t)(bn + srb) * K + k0 + scol,      &bb[(wv * 16) * 32]);
    };

    const int T = K >> 5;
    stage(0, 0);
    __syncthreads();

    for (int t = 0; t < T; ++t) {
        const int cur = t & 1;
        if (t + 1 < T) stage(cur ^ 1, (t + 1) << 5);
        __builtin_amdgcn_sched_barrier(0);

        const unsigned short* ab = As + cur * 4096;
        const unsigned short* bb = Bs + cur * 2048;
        bf16x8 af[4], bf[2];
#pragma unroll
        for (int m = 0; m < 4; ++m)
            af[m] = *(const bf16x8*)&ab[(wr * 64 + m * 16 + lr) * 32 + lq * 8];
#pragma unroll
        for (int n = 0; n < 2; ++n)
            bf[n] = *(const bf16x8*)&bb[(wc * 32 + n * 16 + lr) * 32 + lq * 8];

#pragma unroll
        for (int m = 0; m < 4; ++m)
#pragma unroll
            for (int n = 0; n < 2; ++n)
                acc[m][n] = __builtin_amdgcn_mfma_f32_16x16x32_bf16(af[m], bf[n], acc[m][n], 0, 0, 0);

        __syncthreads();
    }

#pragma unroll
    for (int n = 0; n < 2; ++n) {
        const int col = bn + wc * 32 + n * 16 + lr;
        const float bcol = bias[col];
#pragma unroll
        for (int m = 0; m < 4; ++m) {
#pragma unroll
            for (int r = 0; r < 4; ++r) {
                const int row = bm + wr * 64 + m * 16 + lq * 4 + r;
                float v = acc[m][n][r] + bcol;
                v *= scale;
                if (RELU) v = fmaxf(v, 0.0f);
                if (RES)  v += res[(size_t)row * N + col];
                if (OUTBF) ((unsigned short*)Cout)[(size_t)row * N + col] = f2bf(v);
                else       ((float*)Cout)[(size_t)row * N + col] = v;
            }
        }
    }
}

// Fused Q/K/V^T projections: 768 blocks (3/CU).
__global__ __launch_bounds__(256) void qkv_fused(const unsigned short* __restrict__ h,
                                                 const unsigned short* __restrict__ Wq,
                                                 const unsigned short* __restrict__ Wk,
                                                 const unsigned short* __restrict__ Wv,
                                                 const float* __restrict__ bq,
                                                 const float* __restrict__ bk,
                                                 const float* __restrict__ bv,
                                                 unsigned short* __restrict__ qo,
                                                 unsigned short* __restrict__ ko,
                                                 unsigned short* __restrict__ vto) {
    __shared__ unsigned short As[2 * 4096];
    __shared__ unsigned short Bs[2 * 4096];
    const int id = blockIdx.x;
    const int op = id >> 8;
    const int t  = id & 255;
    if (op == 0) {
        gemm_core<false, false, true, false>(h, Wq, bq, nullptr, qo,
            ROWS, D_MODEL, D_MODEL, QSCALE, (t >> 3) * 128, (t & 7) * 128, As, Bs);
    } else if (op == 1) {
        gemm_core<false, false, true, false>(h, Wk, bk, nullptr, ko,
            ROWS, D_MODEL, D_MODEL, 1.0f, (t >> 3) * 128, (t & 7) * 128, As, Bs);
    } else {
        gemm_core<false, false, true, true>(Wv, h, bv, nullptr, vto,
            D_MODEL, ROWS, D_MODEL, 1.0f, (t >> 5) * 128, (t & 31) * 128, As, Bs);
    }
}

// ---------------------------------------------------------------------------
// bf16 MFMA flash attention, swapped-QK^T, single-barrier LDS double-buffer,
// defer-max (T13) + setprio (T5). Softmax in exp2 domain (Q pre-scaled).
// ---------------------------------------------------------------------------
__global__ __launch_bounds__(256) void attn_mfma(const unsigned short* __restrict__ Q,
                                                 const unsigned short* __restrict__ K,
                                                 const unsigned short* __restrict__ Vt,
                                                 const float* __restrict__ mbias,
                                                 const int* __restrict__ tflag,
                                                 unsigned short* __restrict__ O) {
    __shared__ unsigned short Ks[2][64][68];
    __shared__ unsigned short Vs[2][64][68];
    __shared__ unsigned short Ps[64][68];

    const int bh = blockIdx.x, qt = blockIdx.y;
    const int b = bh >> 4, h = bh & 15;
    const int q0 = qt * 64;
    const int tid = threadIdx.x;
    const int w = tid >> 6, lane = tid & 63;
    const int lr = lane & 15, lq = lane >> 4;

    const size_t qkbase = (size_t)b * SS * D_MODEL + (size_t)h * DK;
    const int tok0 = b * SS;
    const float* mb = mbias + (size_t)b * SS;
    const int* tf = tflag + b * (SS / 64);

    const unsigned short* qp = Q + qkbase + (size_t)(q0 + w * 16 + lr) * D_MODEL;
    const bf16x8 qf0 = *(const bf16x8*)(qp + lq * 8);
    const bf16x8 qf1 = *(const bf16x8*)(qp + 32 + lq * 8);

    const int sr = tid >> 3, sch = tid & 7;
    bf16x8 kreg0, kreg1, vreg0, vreg1;
    {
        const unsigned short* kp = K + qkbase + (size_t)sr * D_MODEL + sch * 8;
        kreg0 = *(const bf16x8*)(kp);
        kreg1 = *(const bf16x8*)(kp + 32 * D_MODEL);
        const unsigned short* vp = Vt + (size_t)(h * DK + sr) * ROWS + tok0 + sch * 8;
        vreg0 = *(const bf16x8*)(vp);
        vreg1 = *(const bf16x8*)(vp + 32 * ROWS);
    }
    *(bf16x8*)&Ks[0][sr][sch * 8]      = kreg0;
    *(bf16x8*)&Ks[0][sr + 32][sch * 8] = kreg1;
    *(bf16x8*)&Vs[0][sr][sch * 8]      = vreg0;
    *(bf16x8*)&Vs[0][sr + 32][sch * 8] = vreg1;
    __syncthreads();

    f32x4 acc_o[4];
#pragma unroll
    for (int n = 0; n < 4; ++n) acc_o[n] = (f32x4){0.f, 0.f, 0.f, 0.f};
    float m_run = -1e30f, l_run = 0.0f;

    const int NT = SS / 64;
    for (int kt = 0; kt < NT; ++kt) {
        const int cur = kt & 1;
        if (kt + 1 < NT) {      // issue next tile's global loads early (T14)
            const int k1 = (kt + 1) * 64;
            const unsigned short* kp = K + qkbase + (size_t)(k1 + sr) * D_MODEL + sch * 8;
            kreg0 = *(const bf16x8*)(kp);
            kreg1 = *(const bf16x8*)(kp + 32 * D_MODEL);
            const unsigned short* vp = Vt + (size_t)(h * DK + sr) * ROWS + tok0 + k1 + sch * 8;
            vreg0 = *(const bf16x8*)(vp);
            vreg1 = *(const bf16x8*)(vp + 32 * ROWS);
        }

        // S^T = mfma(K, Q): lane holds q=lr; keys k = n*16 + lq*4 + r
        f32x4 sa[4];
#pragma unroll
        for (int n = 0; n < 4; ++n) sa[n] = (f32x4){0.f, 0.f, 0.f, 0.f};
        __builtin_amdgcn_s_setprio(1);
#pragma unroll
        for (int n = 0; n < 4; ++n) {
            bf16x8 kf0 = *(const bf16x8*)&Ks[cur][n * 16 + lr][lq * 8];
            bf16x8 kf1 = *(const bf16x8*)&Ks[cur][n * 16 + lr][32 + lq * 8];
            sa[n] = __builtin_amdgcn_mfma_f32_16x16x32_bf16(kf0, qf0, sa[n], 0, 0, 0);
            sa[n] = __builtin_amdgcn_mfma_f32_16x16x32_bf16(kf1, qf1, sa[n], 0, 0, 0);
        }
        __builtin_amdgcn_s_setprio(0);

        if (tf[kt]) {
#pragma unroll
            for (int n = 0; n < 4; ++n) {
                F4 m4; m4.v = *(const float4*)&mb[kt * 64 + n * 16 + lq * 4];
#pragma unroll
                for (int r = 0; r < 4; ++r) sa[n][r] += m4.f[r];
            }
        }

        // online softmax with defer-max (per-lane q-row = lr)
        float pmax = sa[0][0];
#pragma unroll
        for (int n = 0; n < 4; ++n)
#pragma unroll
            for (int r = 0; r < 4; ++r) pmax = fmaxf(pmax, sa[n][r]);
        pmax = fmaxf(pmax, __shfl_xor(pmax, 16));
        pmax = fmaxf(pmax, __shfl_xor(pmax, 32));

        if (!__all(pmax - m_run <= DEFER_THR)) {
            const float mn = fmaxf(m_run, pmax);
            const float sc = exp2_fast(m_run - mn);
            m_run = mn;
            l_run *= sc;
#pragma unroll
            for (int n = 0; n < 4; ++n) {
                acc_o[n][0] *= sc; acc_o[n][1] *= sc; acc_o[n][2] *= sc; acc_o[n][3] *= sc;
            }
        }
        float rs = 0.0f;
#pragma unroll
        for (int n = 0; n < 4; ++n)
#pragma unroll
            for (int r = 0; r < 4; ++r) {
                const float p = exp2_fast(sa[n][r] - m_run);
                sa[n][r] = p;
                rs += p;
            }
        rs += __shfl_xor(rs, 16);
        rs += __shfl_xor(rs, 32);
        l_run += rs;

        // pack P (bf16) -> wave-private LDS rows
#pragma unroll
        for (int n = 0; n < 4; ++n) {
            uint2 u;
            u.x = cvt_pk_bf16(sa[n][0], sa[n][1]);
            u.y = cvt_pk_bf16(sa[n][2], sa[n][3]);
            *(uint2*)&Ps[w * 16 + lr][n * 16 + lq * 4] = u;
        }

        // PV: O^T[d][q] += Vt[d][k] * P^T[k][q]
        __builtin_amdgcn_s_setprio(1);
#pragma unroll
        for (int c = 0; c < 2; ++c) {
            bf16x8 pf = *(const bf16x8*)&Ps[w * 16 + lr][c * 32 + lq * 8];
#pragma unroll
            for (int n = 0; n < 4; ++n) {
                bf16x8 vf = *(const bf16x8*)&Vs[cur][n * 16 + lr][c * 32 + lq * 8];
                acc_o[n] = __builtin_amdgcn_mfma_f32_16x16x32_bf16(vf, pf, acc_o[n], 0, 0, 0);
            }
        }
        __builtin_amdgcn_s_setprio(0);

        if (kt + 1 < NT) {      // write prefetched tile into the other buffer
            *(bf16x8*)&Ks[cur ^ 1][sr][sch * 8]      = kreg0;
            *(bf16x8*)&Ks[cur ^ 1][sr + 32][sch * 8] = kreg1;
            *(bf16x8*)&Vs[cur ^ 1][sr][sch * 8]      = vreg0;
            *(bf16x8*)&Vs[cur ^ 1][sr + 32][sch * 8] = vreg1;
        }
        __syncthreads();
    }

    const float invl = 1.0f / l_run;
    unsigned short* orow = O + qkbase + (size_t)(q0 + w * 16 + lr) * D_MODEL;
#pragma unroll
    for (int n = 0; n < 4; ++n) {
        ushort4 o;
        o.x = f2bf(acc_o[n][0] * invl);
        o.y = f2bf(acc_o[n][1] * invl);
        o.z = f2bf(acc_o[n][2] * invl);
        o.w = f2bf(acc_o[n][3] * invl);
        *(ushort4*)(orow + n * 16 + lq * 4) = o;
    }
}

// ---------------------------------------------------------------------------
extern "C" void kernel_launch(void* const* d_in, const int* in_sizes, int n_in,
                              void* d_out, int out_size, void* d_ws, size_t ws_size,
                              hipStream_t stream) {
    const float* x   = (const float*)d_in[0];
    const int*   msk = (const int*)d_in[1];
    const float* Wq  = (const float*)d_in[2];
    const float* bq  = (const float*)d_in[3];
    const float* Wk  = (const float*)d_in[4];
    const float* bk  = (const float*)d_in[5];
    const float* Wv  = (const float*)d_in[6];
    const float* bv  = (const float*)d_in[7];
    const float* Wo  = (const float*)d_in[8];
    const float* bo  = (const float*)d_in[9];
    const float* W1  = (const float*)d_in[10];
    const float* b1  = (const float*)d_in[11];
    const float* W2  = (const float*)d_in[12];
    const float* b2  = (const float*)d_in[13];
    const float* g1  = (const float*)d_in[14];
    const float* be1 = (const float*)d_in[15];
    const float* g2  = (const float*)d_in[16];
    const float* be2 = (const float*)d_in[17];
    float* out = (float*)d_out;

    char* w = (char*)d_ws;
    unsigned short* h_bf   = (unsigned short*)w; w += (size_t)ROWS * D_MODEL * 2;
    unsigned short* qb_bf  = (unsigned short*)w; w += (size_t)ROWS * D_MODEL * 2;
    unsigned short* kb_bf  = (unsigned short*)w; w += (size_t)ROWS * D_MODEL * 2;
    unsigned short* vt_bf  = (unsigned short*)w; w += (size_t)ROWS * D_MODEL * 2;
    unsigned short* ctx_bf = (unsigned short*)w; w += (size_t)ROWS * D_MODEL * 2;
    float* xat             = (float*)w;          w += (size_t)ROWS * D_MODEL * 4;
    unsigned short* h2_bf  = (unsigned short*)w; w += (size_t)ROWS * D_MODEL * 2;
    unsigned short* ff1_bf = (unsigned short*)w; w += (size_t)ROWS * D_FF * 2;
    unsigned short* Wq_bf  = (unsigned short*)w; w += (size_t)D_MODEL * D_MODEL * 2;
    unsigned short* Wk_bf  = (unsigned short*)w; w += (size_t)D_MODEL * D_MODEL * 2;
    unsigned short* Wv_bf  = (unsigned short*)w; w += (size_t)D_MODEL * D_MODEL * 2;
    unsigned short* Wo_bf  = (unsigned short*)w; w += (size_t)D_MODEL * D_MODEL * 2;
    unsigned short* W1_bf  = (unsigned short*)w; w += (size_t)D_FF * D_MODEL * 2;
    unsigned short* W2_bf  = (unsigned short*)w; w += (size_t)D_FF * D_MODEL * 2;
    float* mbias           = (float*)w;          w += (size_t)ROWS * 4;
    int* tflag             = (int*)w;            w += (size_t)(BB * SS / 64) * 4;

    const dim3 blk(256);
    cast_all<<<2048, blk, 0, stream>>>(Wq, Wk, Wv, Wo, W1, W2,
                                       Wq_bf, Wk_bf, Wv_bf, Wo_bf, W1_bf, W2_bf);
    mask_prep<<<ROWS / 256, blk, 0, stream>>>(msk, mbias, tflag);

    ln_bf16_kernel<<<ROWS, blk, 0, stream>>>(x, g1, be1, h_bf);

    qkv_fused<<<768, blk, 0, stream>>>(h_bf, Wq_bf, Wk_bf, Wv_bf, bq, bk, bv,
                                       qb_bf, kb_bf, vt_bf);

    attn_mfma<<<dim3(BB * N_HEADS, SS / 64), blk, 0, stream>>>(qb_bf, kb_bf, vt_bf,
                                                               mbias, tflag, ctx_bf);

    // O-proj + residual: 128x64 tiles -> 512 blocks (2/CU)
    gemm_n64<false, true, false><<<dim3(D_MODEL / 64, ROWS / 128), blk, 0, stream>>>(
        ctx_bf, Wo_bf, bo, x, xat, ROWS, D_MODEL, D_MODEL, 1.0f);

    ln_bf16_kernel<<<ROWS, blk, 0, stream>>>(xat, g2, be2, h2_bf);

    // FFN1: 128x128, 1024 blocks (4/CU)
    gemm_bf16<true, false, true, false><<<dim3(D_FF / 128, ROWS / 128), blk, 0, stream>>>(
        h2_bf, W1_bf, b1, nullptr, ff1_bf, ROWS, D_FF, D_MODEL, 1.0f);

    // FFN2 + residual: 128x64 tiles -> 512 blocks (2/CU)
    gemm_n64<false, true, false><<<dim3(D_MODEL / 64, ROWS / 128), blk, 0, stream>>>(
        ff1_bf, W2_bf, b2, xat, out, ROWS, D_MODEL, D_FF, 1.0f);
}

// Round 7
// 386.092 us; speedup vs baseline: 6.0941x; 1.0511x over previous
//
#include <hip/hip_runtime.h>
#include <math.h>

#define D_MODEL 1024
#define N_HEADS 16
#define DK      64
#define D_FF    4096
#define BB      2
#define SS      2048
#define ROWS    (BB * SS)
#define EPS     1e-8f
#define NEG     -1e9f
#define QSCALE  0.1803368801111f   // 0.125 * log2(e): softmax in exp2 domain
#define DEFER_THR 11.541560327f    // 8 * log2(e)

union F4 { float4 v; float f[4]; };

typedef __attribute__((ext_vector_type(8))) short   bf16x8;
typedef __attribute__((ext_vector_type(4))) float   f32x4;

__device__ __forceinline__ unsigned short f2bf(float f) {
    union { float f; unsigned u; } a; a.f = f;
    unsigned r = a.u + 0x7FFFu + ((a.u >> 16) & 1u);
    return (unsigned short)(r >> 16);
}

__device__ __forceinline__ float exp2_fast(float x) {
    float r;
    asm("v_exp_f32 %0, %1" : "=v"(r) : "v"(x));
    return r;
}

__device__ __forceinline__ unsigned cvt_pk_bf16(float lo, float hi) {
    unsigned r;
    asm("v_cvt_pk_bf16_f32 %0, %1, %2" : "=v"(r) : "v"(lo), "v"(hi));
    return r;
}

__device__ __forceinline__ void gload16(const void* g, void* l) {
    __builtin_amdgcn_global_load_lds(
        (const __attribute__((address_space(1))) unsigned int*)g,
        (__attribute__((address_space(3))) unsigned int*)l, 16, 0, 0);
}

// ---------------------------------------------------------------------------
// LayerNorm -> bf16 (torch semantics: mean, ddof=1 std, eps on std)
// ---------------------------------------------------------------------------
__global__ __launch_bounds__(256) void ln_bf16_kernel(const float* __restrict__ x,
                                                      const float* __restrict__ g,
                                                      const float* __restrict__ be,
                                                      unsigned short* __restrict__ out) {
    __shared__ float sm[8];
    const int row = blockIdx.x;
    float4 v = ((const float4*)(x + (size_t)row * D_MODEL))[threadIdx.x];

    float s = v.x + v.y + v.z + v.w;
#pragma unroll
    for (int o = 32; o; o >>= 1) s += __shfl_xor(s, o);
    const int wid = threadIdx.x >> 6, lane = threadIdx.x & 63;
    if (lane == 0) sm[wid] = s;
    __syncthreads();
    const float mean = (sm[0] + sm[1] + sm[2] + sm[3]) * (1.0f / D_MODEL);

    const float dx = v.x - mean, dy = v.y - mean, dz = v.z - mean, dw = v.w - mean;
    float sq = dx * dx + dy * dy + dz * dz + dw * dw;
#pragma unroll
    for (int o = 32; o; o >>= 1) sq += __shfl_xor(sq, o);
    if (lane == 0) sm[4 + wid] = sq;
    __syncthreads();
    const float var = (sm[4] + sm[5] + sm[6] + sm[7]) * (1.0f / (D_MODEL - 1));
    const float inv = 1.0f / (sqrtf(var) + EPS);
    const float g0 = g[0], b0 = be[0];

    ushort4 o4;
    o4.x = f2bf(g0 * dx * inv + b0);
    o4.y = f2bf(g0 * dy * inv + b0);
    o4.z = f2bf(g0 * dz * inv + b0);
    o4.w = f2bf(g0 * dw * inv + b0);
    ((ushort4*)(out + (size_t)row * D_MODEL))[threadIdx.x] = o4;
}

// ---------------------------------------------------------------------------
// Fused: cast ALL weights -> bf16 (grid-stride) + mask prep (first 4096 idx).
// ---------------------------------------------------------------------------
__global__ __launch_bounds__(256) void cast_all(const float* __restrict__ s0,
                                                const float* __restrict__ s1,
                                                const float* __restrict__ s2,
                                                const float* __restrict__ s3,
                                                const float* __restrict__ s4,
                                                const float* __restrict__ s5,
                                                unsigned short* __restrict__ d0,
                                                unsigned short* __restrict__ d1,
                                                unsigned short* __restrict__ d2,
                                                unsigned short* __restrict__ d3,
                                                unsigned short* __restrict__ d4,
                                                unsigned short* __restrict__ d5,
                                                const int* __restrict__ mask,
                                                float* __restrict__ mbias,
                                                int* __restrict__ tflag) {
    const int ND4 = D_MODEL * D_MODEL / 4;   // 2^18
    const int NF4 = D_FF * D_MODEL / 4;      // 2^20
    const int total = 4 * ND4 + 2 * NF4;     // 3*2^20
    for (int i = blockIdx.x * 256 + threadIdx.x; i < total; i += gridDim.x * 256) {
        if (i < ROWS) {   // whole waves (ROWS % 64 == 0): mask prep
            const int m = mask[i];
            mbias[i] = m ? 0.0f : NEG;
            unsigned long long z = __ballot(m == 0);
            if ((threadIdx.x & 63) == 0) tflag[i >> 6] = (z != 0ull) ? 1 : 0;
        }
        const float* s; unsigned short* d; int off;
        if (i < 4 * ND4) {
            const int w = i >> 18;
            off = i & (ND4 - 1);
            s = (w == 0) ? s0 : (w == 1) ? s1 : (w == 2) ? s2 : s3;
            d = (w == 0) ? d0 : (w == 1) ? d1 : (w == 2) ? d2 : d3;
        } else {
            const int j = i - 4 * ND4;
            const int w = j >> 20;
            off = j & (NF4 - 1);
            s = w ? s5 : s4;
            d = w ? d5 : d4;
        }
        float4 v = ((const float4*)s)[off];
        ushort4 o = { f2bf(v.x), f2bf(v.y), f2bf(v.z), f2bf(v.w) };
        ((ushort4*)d)[off] = o;
    }
}

// ---------------------------------------------------------------------------
// bf16 MFMA GEMM core, 128x128 tile, BK=32, double-buffered LDS (2-phase).
// ---------------------------------------------------------------------------
template <bool RELU, bool RES, bool OUTBF, bool BROW>
__device__ __forceinline__ void gemm_core(const unsigned short* __restrict__ A,
                                          const unsigned short* __restrict__ B,
                                          const float* __restrict__ bias,
                                          const float* __restrict__ res,
                                          void* __restrict__ Cout,
                                          int M, int N, int K, float scale,
                                          int bm, int bn,
                                          unsigned short* As, unsigned short* Bs) {
    const int tid  = threadIdx.x;
    const int lane = tid & 63;
    const int wv   = tid >> 6;
    const int wr   = wv >> 1, wc = wv & 1;
    const int lr   = lane & 15, lq = lane >> 4;

    f32x4 acc[4][4];
#pragma unroll
    for (int m = 0; m < 4; ++m)
#pragma unroll
        for (int n = 0; n < 4; ++n)
            acc[m][n] = (f32x4){0.f, 0.f, 0.f, 0.f};

    const int srow = wv * 32 + (lane >> 2);
    const int scol = (lane & 3) * 8;

    auto stage = [&](int buf, int k0) {
        unsigned short* ab = As + buf * 4096;
        unsigned short* bb = Bs + buf * 4096;
        gload16(A + (size_t)(bm + srow) * K + k0 + scol,      &ab[(wv * 32) * 32]);
        gload16(A + (size_t)(bm + srow + 16) * K + k0 + scol, &ab[(wv * 32 + 16) * 32]);
        gload16(B + (size_t)(bn + srow) * K + k0 + scol,      &bb[(wv * 32) * 32]);
        gload16(B + (size_t)(bn + srow + 16) * K + k0 + scol, &bb[(wv * 32 + 16) * 32]);
    };

    const int T = K >> 5;
    stage(0, 0);
    __syncthreads();

    for (int t = 0; t < T; ++t) {
        const int cur = t & 1;
        if (t + 1 < T) stage(cur ^ 1, (t + 1) << 5);
        __builtin_amdgcn_sched_barrier(0);

        const unsigned short* ab = As + cur * 4096;
        const unsigned short* bb = Bs + cur * 4096;
        bf16x8 af[4], bf[4];
#pragma unroll
        for (int m = 0; m < 4; ++m)
            af[m] = *(const bf16x8*)&ab[(wr * 64 + m * 16 + lr) * 32 + lq * 8];
#pragma unroll
        for (int n = 0; n < 4; ++n)
            bf[n] = *(const bf16x8*)&bb[(wc * 64 + n * 16 + lr) * 32 + lq * 8];

#pragma unroll
        for (int m = 0; m < 4; ++m)
#pragma unroll
            for (int n = 0; n < 4; ++n)
                acc[m][n] = __builtin_amdgcn_mfma_f32_16x16x32_bf16(af[m], bf[n], acc[m][n], 0, 0, 0);

        __syncthreads();
    }

#pragma unroll
    for (int n = 0; n < 4; ++n) {
        const int col = bn + wc * 64 + n * 16 + lr;
        const float bcol = BROW ? 0.0f : bias[col];
#pragma unroll
        for (int m = 0; m < 4; ++m) {
#pragma unroll
            for (int r = 0; r < 4; ++r) {
                const int row = bm + wr * 64 + m * 16 + lq * 4 + r;
                float v = acc[m][n][r] + (BROW ? bias[row] : bcol);
                v *= scale;
                if (RELU) v = fmaxf(v, 0.0f);
                if (RES)  v += res[(size_t)row * N + col];
                if (OUTBF) ((unsigned short*)Cout)[(size_t)row * N + col] = f2bf(v);
                else       ((float*)Cout)[(size_t)row * N + col] = v;
            }
        }
    }
}

template <bool RELU, bool RES, bool OUTBF, bool BROW>
__global__ __launch_bounds__(256) void gemm_bf16(const unsigned short* __restrict__ A,
                                                 const unsigned short* __restrict__ B,
                                                 const float* __restrict__ bias,
                                                 const float* __restrict__ res,
                                                 void* __restrict__ Cout,
                                                 int M, int N, int K, float scale) {
    __shared__ unsigned short As[2 * 4096];
    __shared__ unsigned short Bs[2 * 4096];
    gemm_core<RELU, RES, OUTBF, BROW>(A, B, bias, res, Cout, M, N, K, scale,
                                      blockIdx.y * 128, blockIdx.x * 128, As, Bs);
}

// ---------------------------------------------------------------------------
// Split-K GEMM: 128x128 tile, blockIdx.z selects K-half; fp32 partials out.
// ---------------------------------------------------------------------------
__global__ __launch_bounds__(256) void gemm_splitk(const unsigned short* __restrict__ A,
                                                   const unsigned short* __restrict__ B,
                                                   float* __restrict__ Cpart,
                                                   int M, int N, int K, int klen) {
    __shared__ unsigned short As[2 * 4096];
    __shared__ unsigned short Bs[2 * 4096];

    const int bm = blockIdx.y * 128;
    const int bn = blockIdx.x * 128;
    const int kb0 = blockIdx.z * klen;
    float* Cz = Cpart + (size_t)blockIdx.z * M * N;

    const int tid  = threadIdx.x;
    const int lane = tid & 63;
    const int wv   = tid >> 6;
    const int wr   = wv >> 1, wc = wv & 1;
    const int lr   = lane & 15, lq = lane >> 4;

    f32x4 acc[4][4];
#pragma unroll
    for (int m = 0; m < 4; ++m)
#pragma unroll
        for (int n = 0; n < 4; ++n)
            acc[m][n] = (f32x4){0.f, 0.f, 0.f, 0.f};

    const int srow = wv * 32 + (lane >> 2);
    const int scol = (lane & 3) * 8;

    auto stage = [&](int buf, int k0) {
        unsigned short* ab = As + buf * 4096;
        unsigned short* bb = Bs + buf * 4096;
        gload16(A + (size_t)(bm + srow) * K + k0 + scol,      &ab[(wv * 32) * 32]);
        gload16(A + (size_t)(bm + srow + 16) * K + k0 + scol, &ab[(wv * 32 + 16) * 32]);
        gload16(B + (size_t)(bn + srow) * K + k0 + scol,      &bb[(wv * 32) * 32]);
        gload16(B + (size_t)(bn + srow + 16) * K + k0 + scol, &bb[(wv * 32 + 16) * 32]);
    };

    const int T = klen >> 5;
    stage(0, kb0);
    __syncthreads();

    for (int t = 0; t < T; ++t) {
        const int cur = t & 1;
        if (t + 1 < T) stage(cur ^ 1, kb0 + ((t + 1) << 5));
        __builtin_amdgcn_sched_barrier(0);

        const unsigned short* ab = As + cur * 4096;
        const unsigned short* bb = Bs + cur * 4096;
        bf16x8 af[4], bf[4];
#pragma unroll
        for (int m = 0; m < 4; ++m)
            af[m] = *(const bf16x8*)&ab[(wr * 64 + m * 16 + lr) * 32 + lq * 8];
#pragma unroll
        for (int n = 0; n < 4; ++n)
            bf[n] = *(const bf16x8*)&bb[(wc * 64 + n * 16 + lr) * 32 + lq * 8];

#pragma unroll
        for (int m = 0; m < 4; ++m)
#pragma unroll
            for (int n = 0; n < 4; ++n)
                acc[m][n] = __builtin_amdgcn_mfma_f32_16x16x32_bf16(af[m], bf[n], acc[m][n], 0, 0, 0);

        __syncthreads();
    }

#pragma unroll
    for (int n = 0; n < 4; ++n) {
        const int col = bn + wc * 64 + n * 16 + lr;
#pragma unroll
        for (int m = 0; m < 4; ++m)
#pragma unroll
            for (int r = 0; r < 4; ++r) {
                const int row = bm + wr * 64 + m * 16 + lq * 4 + r;
                Cz[(size_t)row * N + col] = acc[m][n][r];
            }
    }
}

// out = p0 + p1 + bias[col] + res   (fp32, float4-vectorized)
__global__ __launch_bounds__(256) void ffn2_combine(const float* __restrict__ p0,
                                                    const float* __restrict__ p1,
                                                    const float* __restrict__ bias,
                                                    const float* __restrict__ res,
                                                    float* __restrict__ out) {
    const int i = blockIdx.x * 256 + threadIdx.x;       // over ROWS*D_MODEL/4
    const int c4 = i & (D_MODEL / 4 - 1);
    float4 a = ((const float4*)p0)[i];
    float4 b = ((const float4*)p1)[i];
    float4 r = ((const float4*)res)[i];
    float4 bb = ((const float4*)bias)[c4];
    float4 o;
    o.x = a.x + b.x + bb.x + r.x;
    o.y = a.y + b.y + bb.y + r.y;
    o.z = a.z + b.z + bb.z + r.z;
    o.w = a.w + b.w + bb.w + r.w;
    ((float4*)out)[i] = o;
}

// ---------------------------------------------------------------------------
// 128x64-tile GEMM for N=1024 outputs (O-proj): 512 blocks = 2/CU.
// ---------------------------------------------------------------------------
template <bool RELU, bool RES, bool OUTBF>
__global__ __launch_bounds__(256) void gemm_n64(const unsigned short* __restrict__ A,
                                                const unsigned short* __restrict__ B,
                                                const float* __restrict__ bias,
                                                const float* __restrict__ res,
                                                void* __restrict__ Cout,
                                                int M, int N, int K, float scale) {
    __shared__ unsigned short As[2 * 4096];   // 128 rows x 32
    __shared__ unsigned short Bs[2 * 2048];   // 64 rows x 32

    const int bm = blockIdx.y * 128;
    const int bn = blockIdx.x * 64;
    const int tid  = threadIdx.x;
    const int lane = tid & 63;
    const int wv   = tid >> 6;
    const int wr   = wv >> 1, wc = wv & 1;
    const int lr   = lane & 15, lq = lane >> 4;

    f32x4 acc[4][2];
#pragma unroll
    for (int m = 0; m < 4; ++m)
#pragma unroll
        for (int n = 0; n < 2; ++n)
            acc[m][n] = (f32x4){0.f, 0.f, 0.f, 0.f};

    const int sra = wv * 32 + (lane >> 2);
    const int srb = wv * 16 + (lane >> 2);
    const int scol = (lane & 3) * 8;

    auto stage = [&](int buf, int k0) {
        unsigned short* ab = As + buf * 4096;
        unsigned short* bb = Bs + buf * 2048;
        gload16(A + (size_t)(bm + sra) * K + k0 + scol,      &ab[(wv * 32) * 32]);
        gload16(A + (size_t)(bm + sra + 16) * K + k0 + scol, &ab[(wv * 32 + 16) * 32]);
        gload16(B + (size_t)(bn + srb) * K + k0 + scol,      &bb[(wv * 16) * 32]);
    };

    const int T = K >> 5;
    stage(0, 0);
    __syncthreads();

    for (int t = 0; t < T; ++t) {
        const int cur = t & 1;
        if (t + 1 < T) stage(cur ^ 1, (t + 1) << 5);
        __builtin_amdgcn_sched_barrier(0);

        const unsigned short* ab = As + cur * 4096;
        const unsigned short* bb = Bs + cur * 2048;
        bf16x8 af[4], bf[2];
#pragma unroll
        for (int m = 0; m < 4; ++m)
            af[m] = *(const bf16x8*)&ab[(wr * 64 + m * 16 + lr) * 32 + lq * 8];
#pragma unroll
        for (int n = 0; n < 2; ++n)
            bf[n] = *(const bf16x8*)&bb[(wc * 32 + n * 16 + lr) * 32 + lq * 8];

#pragma unroll
        for (int m = 0; m < 4; ++m)
#pragma unroll
            for (int n = 0; n < 2; ++n)
                acc[m][n] = __builtin_amdgcn_mfma_f32_16x16x32_bf16(af[m], bf[n], acc[m][n], 0, 0, 0);

        __syncthreads();
    }

#pragma unroll
    for (int n = 0; n < 2; ++n) {
        const int col = bn + wc * 32 + n * 16 + lr;
        const float bcol = bias[col];
#pragma unroll
        for (int m = 0; m < 4; ++m) {
#pragma unroll
            for (int r = 0; r < 4; ++r) {
                const int row = bm + wr * 64 + m * 16 + lq * 4 + r;
                float v = acc[m][n][r] + bcol;
                v *= scale;
                if (RELU) v = fmaxf(v, 0.0f);
                if (RES)  v += res[(size_t)row * N + col];
                if (OUTBF) ((unsigned short*)Cout)[(size_t)row * N + col] = f2bf(v);
                else       ((float*)Cout)[(size_t)row * N + col] = v;
            }
        }
    }
}

// Fused Q/K/V^T projections: 768 blocks (3/CU).
__global__ __launch_bounds__(256) void qkv_fused(const unsigned short* __restrict__ h,
                                                 const unsigned short* __restrict__ Wq,
                                                 const unsigned short* __restrict__ Wk,
                                                 const unsigned short* __restrict__ Wv,
                                                 const float* __restrict__ bq,
                                                 const float* __restrict__ bk,
                                                 const float* __restrict__ bv,
                                                 unsigned short* __restrict__ qo,
                                                 unsigned short* __restrict__ ko,
                                                 unsigned short* __restrict__ vto) {
    __shared__ unsigned short As[2 * 4096];
    __shared__ unsigned short Bs[2 * 4096];
    const int id = blockIdx.x;
    const int op = id >> 8;
    const int t  = id & 255;
    if (op == 0) {
        gemm_core<false, false, true, false>(h, Wq, bq, nullptr, qo,
            ROWS, D_MODEL, D_MODEL, QSCALE, (t >> 3) * 128, (t & 7) * 128, As, Bs);
    } else if (op == 1) {
        gemm_core<false, false, true, false>(h, Wk, bk, nullptr, ko,
            ROWS, D_MODEL, D_MODEL, 1.0f, (t >> 3) * 128, (t & 7) * 128, As, Bs);
    } else {
        gemm_core<false, false, true, true>(Wv, h, bv, nullptr, vto,
            D_MODEL, ROWS, D_MODEL, 1.0f, (t >> 5) * 128, (t & 31) * 128, As, Bs);
    }
}

// ---------------------------------------------------------------------------
// bf16 MFMA flash attention (R4 structure: single-buffer, 2 barriers/tile,
// reg-prefetch T14) + defer-max (T13). No setprio (hurts lockstep waves).
// ---------------------------------------------------------------------------
__global__ __launch_bounds__(256) void attn_mfma(const unsigned short* __restrict__ Q,
                                                 const unsigned short* __restrict__ K,
                                                 const unsigned short* __restrict__ Vt,
                                                 const float* __restrict__ mbias,
                                                 const int* __restrict__ tflag,
                                                 unsigned short* __restrict__ O) {
    __shared__ unsigned short Ks[64][68];   // [key][d]
    __shared__ unsigned short Vs[64][68];   // [d][key]
    __shared__ unsigned short Ps[64][68];   // [q][key], wave-private rows

    const int bh = blockIdx.x, qt = blockIdx.y;
    const int b = bh >> 4, h = bh & 15;
    const int q0 = qt * 64;
    const int tid = threadIdx.x;
    const int w = tid >> 6, lane = tid & 63;
    const int lr = lane & 15, lq = lane >> 4;

    const size_t qkbase = (size_t)b * SS * D_MODEL + (size_t)h * DK;
    const int tok0 = b * SS;
    const float* mb = mbias + (size_t)b * SS;
    const int* tf = tflag + b * (SS / 64);

    // Q as B-fragments (col = q = lr, k-chunk = lq*8)
    const unsigned short* qp = Q + qkbase + (size_t)(q0 + w * 16 + lr) * D_MODEL;
    const bf16x8 qf0 = *(const bf16x8*)(qp + lq * 8);
    const bf16x8 qf1 = *(const bf16x8*)(qp + 32 + lq * 8);

    // staging: thread covers rows sr, sr+32; 8-elem chunk sch
    const int sr = tid >> 3, sch = tid & 7;
    bf16x8 kreg0, kreg1, vreg0, vreg1;
    {
        const unsigned short* kp = K + qkbase + (size_t)sr * D_MODEL + sch * 8;
        kreg0 = *(const bf16x8*)(kp);
        kreg1 = *(const bf16x8*)(kp + 32 * D_MODEL);
        const unsigned short* vp = Vt + (size_t)(h * DK + sr) * ROWS + tok0 + sch * 8;
        vreg0 = *(const bf16x8*)(vp);
        vreg1 = *(const bf16x8*)(vp + 32 * ROWS);
    }

    f32x4 acc_o[4];
#pragma unroll
    for (int n = 0; n < 4; ++n) acc_o[n] = (f32x4){0.f, 0.f, 0.f, 0.f};
    float m_run = -1e30f, l_run = 0.0f;

    const int NT = SS / 64;
    for (int kt = 0; kt < NT; ++kt) {
        __syncthreads();          // previous tile's LDS reads complete
        *(bf16x8*)&Ks[sr][sch * 8]      = kreg0;
        *(bf16x8*)&Ks[sr + 32][sch * 8] = kreg1;
        *(bf16x8*)&Vs[sr][sch * 8]      = vreg0;
        *(bf16x8*)&Vs[sr + 32][sch * 8] = vreg1;
        __syncthreads();          // staged

        if (kt + 1 < NT) {        // prefetch next K/V tile into regs (T14)
            const int k1 = (kt + 1) * 64;
            const unsigned short* kp = K + qkbase + (size_t)(k1 + sr) * D_MODEL + sch * 8;
            kreg0 = *(const bf16x8*)(kp);
            kreg1 = *(const bf16x8*)(kp + 32 * D_MODEL);
            const unsigned short* vp = Vt + (size_t)(h * DK + sr) * ROWS + tok0 + k1 + sch * 8;
            vreg0 = *(const bf16x8*)(vp);
            vreg1 = *(const bf16x8*)(vp + 32 * ROWS);
        }

        // S^T = mfma(K, Q): lane holds q=lr; keys k = n*16 + lq*4 + r
        f32x4 sa[4];
#pragma unroll
        for (int n = 0; n < 4; ++n) sa[n] = (f32x4){0.f, 0.f, 0.f, 0.f};
#pragma unroll
        for (int n = 0; n < 4; ++n) {
            bf16x8 kf0 = *(const bf16x8*)&Ks[n * 16 + lr][lq * 8];
            bf16x8 kf1 = *(const bf16x8*)&Ks[n * 16 + lr][32 + lq * 8];
            sa[n] = __builtin_amdgcn_mfma_f32_16x16x32_bf16(kf0, qf0, sa[n], 0, 0, 0);
            sa[n] = __builtin_amdgcn_mfma_f32_16x16x32_bf16(kf1, qf1, sa[n], 0, 0, 0);
        }

        if (tf[kt]) {
#pragma unroll
            for (int n = 0; n < 4; ++n) {
                F4 m4; m4.v = *(const float4*)&mb[kt * 64 + n * 16 + lq * 4];
#pragma unroll
                for (int r = 0; r < 4; ++r) sa[n][r] += m4.f[r];
            }
        }

        // online softmax with defer-max (per-lane q-row = lr)
        float pmax = sa[0][0];
#pragma unroll
        for (int n = 0; n < 4; ++n)
#pragma unroll
            for (int r = 0; r < 4; ++r) pmax = fmaxf(pmax, sa[n][r]);
        pmax = fmaxf(pmax, __shfl_xor(pmax, 16));
        pmax = fmaxf(pmax, __shfl_xor(pmax, 32));

        if (!__all(pmax - m_run <= DEFER_THR)) {
            const float mn = fmaxf(m_run, pmax);
            const float sc = exp2_fast(m_run - mn);
            m_run = mn;
            l_run *= sc;
#pragma unroll
            for (int n = 0; n < 4; ++n) {
                acc_o[n][0] *= sc; acc_o[n][1] *= sc; acc_o[n][2] *= sc; acc_o[n][3] *= sc;
            }
        }
        float rs = 0.0f;
#pragma unroll
        for (int n = 0; n < 4; ++n)
#pragma unroll
            for (int r = 0; r < 4; ++r) {
                const float p = exp2_fast(sa[n][r] - m_run);
                sa[n][r] = p;
                rs += p;
            }
        rs += __shfl_xor(rs, 16);
        rs += __shfl_xor(rs, 32);
        l_run += rs;

        // pack P (bf16) -> wave-private LDS rows
#pragma unroll
        for (int n = 0; n < 4; ++n) {
            uint2 u;
            u.x = cvt_pk_bf16(sa[n][0], sa[n][1]);
            u.y = cvt_pk_bf16(sa[n][2], sa[n][3]);
            *(uint2*)&Ps[w * 16 + lr][n * 16 + lq * 4] = u;
        }

        // PV: O^T[d][q] += Vt[d][k] * P^T[k][q]
#pragma unroll
        for (int c = 0; c < 2; ++c) {
            bf16x8 pf = *(const bf16x8*)&Ps[w * 16 + lr][c * 32 + lq * 8];
#pragma unroll
            for (int n = 0; n < 4; ++n) {
                bf16x8 vf = *(const bf16x8*)&Vs[n * 16 + lr][c * 32 + lq * 8];
                acc_o[n] = __builtin_amdgcn_mfma_f32_16x16x32_bf16(vf, pf, acc_o[n], 0, 0, 0);
            }
        }
    }

    const float invl = 1.0f / l_run;
    unsigned short* orow = O + qkbase + (size_t)(q0 + w * 16 + lr) * D_MODEL;
#pragma unroll
    for (int n = 0; n < 4; ++n) {
        ushort4 o;
        o.x = f2bf(acc_o[n][0] * invl);
        o.y = f2bf(acc_o[n][1] * invl);
        o.z = f2bf(acc_o[n][2] * invl);
        o.w = f2bf(acc_o[n][3] * invl);
        *(ushort4*)(orow + n * 16 + lq * 4) = o;
    }
}

// ---------------------------------------------------------------------------
extern "C" void kernel_launch(void* const* d_in, const int* in_sizes, int n_in,
                              void* d_out, int out_size, void* d_ws, size_t ws_size,
                              hipStream_t stream) {
    const float* x   = (const float*)d_in[0];
    const int*   msk = (const int*)d_in[1];
    const float* Wq  = (const float*)d_in[2];
    const float* bq  = (const float*)d_in[3];
    const float* Wk  = (const float*)d_in[4];
    const float* bk  = (const float*)d_in[5];
    const float* Wv  = (const float*)d_in[6];
    const float* bv  = (const float*)d_in[7];
    const float* Wo  = (const float*)d_in[8];
    const float* bo  = (const float*)d_in[9];
    const float* W1  = (const float*)d_in[10];
    const float* b1  = (const float*)d_in[11];
    const float* W2  = (const float*)d_in[12];
    const float* b2  = (const float*)d_in[13];
    const float* g1  = (const float*)d_in[14];
    const float* be1 = (const float*)d_in[15];
    const float* g2  = (const float*)d_in[16];
    const float* be2 = (const float*)d_in[17];
    float* out = (float*)d_out;

    char* w = (char*)d_ws;
    unsigned short* h_bf   = (unsigned short*)w; w += (size_t)ROWS * D_MODEL * 2;
    unsigned short* qb_bf  = (unsigned short*)w; w += (size_t)ROWS * D_MODEL * 2;
    unsigned short* kb_bf  = (unsigned short*)w; w += (size_t)ROWS * D_MODEL * 2;
    unsigned short* vt_bf  = (unsigned short*)w; w += (size_t)ROWS * D_MODEL * 2;
    unsigned short* ctx_bf = (unsigned short*)w; w += (size_t)ROWS * D_MODEL * 2;
    float* xat             = (float*)w;          w += (size_t)ROWS * D_MODEL * 4;
    unsigned short* h2_bf  = (unsigned short*)w; w += (size_t)ROWS * D_MODEL * 2;
    unsigned short* ff1_bf = (unsigned short*)w; w += (size_t)ROWS * D_FF * 2;
    unsigned short* Wq_bf  = (unsigned short*)w; w += (size_t)D_MODEL * D_MODEL * 2;
    unsigned short* Wk_bf  = (unsigned short*)w; w += (size_t)D_MODEL * D_MODEL * 2;
    unsigned short* Wv_bf  = (unsigned short*)w; w += (size_t)D_MODEL * D_MODEL * 2;
    unsigned short* Wo_bf  = (unsigned short*)w; w += (size_t)D_MODEL * D_MODEL * 2;
    unsigned short* W1_bf  = (unsigned short*)w; w += (size_t)D_FF * D_MODEL * 2;
    unsigned short* W2_bf  = (unsigned short*)w; w += (size_t)D_FF * D_MODEL * 2;
    float* mbias           = (float*)w;          w += (size_t)ROWS * 4;
    int* tflag             = (int*)w;            w += (size_t)(BB * SS / 64) * 4;

    // FFN2 split-K partials reuse the (dead by then) qb..ctx region: 32 MB.
    float* part = (float*)qb_bf;   // [2][ROWS][D_MODEL] fp32

    const dim3 blk(256);
    cast_all<<<2048, blk, 0, stream>>>(Wq, Wk, Wv, Wo, W1, W2,
                                       Wq_bf, Wk_bf, Wv_bf, Wo_bf, W1_bf, W2_bf,
                                       msk, mbias, tflag);

    ln_bf16_kernel<<<ROWS, blk, 0, stream>>>(x, g1, be1, h_bf);

    qkv_fused<<<768, blk, 0, stream>>>(h_bf, Wq_bf, Wk_bf, Wv_bf, bq, bk, bv,
                                       qb_bf, kb_bf, vt_bf);

    attn_mfma<<<dim3(BB * N_HEADS, SS / 64), blk, 0, stream>>>(qb_bf, kb_bf, vt_bf,
                                                               mbias, tflag, ctx_bf);

    // O-proj + residual: 128x64 tiles -> 512 blocks (2/CU)
    gemm_n64<false, true, false><<<dim3(D_MODEL / 64, ROWS / 128), blk, 0, stream>>>(
        ctx_bf, Wo_bf, bo, x, xat, ROWS, D_MODEL, D_MODEL, 1.0f);

    ln_bf16_kernel<<<ROWS, blk, 0, stream>>>(xat, g2, be2, h2_bf);

    // FFN1: 128x128, 1024 blocks (4/CU)
    gemm_bf16<true, false, true, false><<<dim3(D_FF / 128, ROWS / 128), blk, 0, stream>>>(
        h2_bf, W1_bf, b1, nullptr, ff1_bf, ROWS, D_FF, D_MODEL, 1.0f);

    // FFN2 via split-K=2: 512 blocks (2/CU), then fused combine (+bias+res)
    gemm_splitk<<<dim3(D_MODEL / 128, ROWS / 128, 2), blk, 0, stream>>>(
        ff1_bf, W2_bf, part, ROWS, D_MODEL, D_FF, D_FF / 2);
    ffn2_combine<<<ROWS * D_MODEL / 4 / 256, blk, 0, stream>>>(
        part, part + (size_t)ROWS * D_MODEL, b2, xat, out);
}